// Round 7
// baseline (8378.072 us; speedup 1.0000x reference)
//
#include <hip/hip_runtime.h>
#include <math.h>

typedef unsigned short u16;
typedef unsigned int   u32;
typedef unsigned long long u64;
typedef __attribute__((ext_vector_type(8))) short bf16x8;
typedef __attribute__((ext_vector_type(4))) float f32x4;

#define DEVI static __device__ __forceinline__

DEVI float bf2f(u16 u){ u32 x = ((u32)u) << 16; float f; __builtin_memcpy(&f, &x, 4); return f; }
DEVI u16 f2bf(float f){ u32 x; __builtin_memcpy(&x, &f, 4); u32 r = (x + 0x7fffu + ((x >> 16) & 1u)) >> 16; return (u16)r; }
DEVI float sigm(float x){ return 1.f / (1.f + __expf(-x)); }
DEVI float tanh_f(float x){ float e = __expf(2.f * x); return 1.f - 2.f / (e + 1.f); }

// ---------------- pack kernels ----------------
__global__ void k_pack_whh2(const float* __restrict__ Wf, const float* __restrict__ Wb, u16* __restrict__ out){
  int blk = blockIdx.x;             // 2*1024
  int d = blk >> 10, n = blk & 1023;
  const float* W = d ? Wb : Wf;
  int k = threadIdx.x;
  out[((size_t)d * 1024 + n) * 256 + k] = f2bf(W[(size_t)k * 1024 + n]);
}

// decoder weights transposed: decwt[n][k], n = gate*256+hc, k<512 -> Wih row 128+k, else Whh row k-512
__global__ void k_pack_decwt(const float* __restrict__ Wih, const float* __restrict__ Whh, u16* __restrict__ out){
  int n = blockIdx.x;               // 1024
  for (int k = threadIdx.x; k < 768; k += 256){
    const float* row = (k < 512) ? (Wih + (size_t)(128 + k) * 1024) : (Whh + (size_t)(k - 512) * 1024);
    out[(size_t)n * 768 + k] = f2bf(row[n]);
  }
}

// vW [768][32000] f32 -> vWt [32000][768] bf16
__global__ __launch_bounds__(256) void k_pack_vwt(const float* __restrict__ vW, u16* __restrict__ vWt){
  __shared__ float ts[64][65];
  int nt = blockIdx.x, kt = blockIdx.y;   // 500 x 12
  int tid = threadIdx.x;
#pragma unroll
  for (int i = 0; i < 16; ++i){
    int idx = tid + i * 256;
    int kl = idx >> 6, nl = idx & 63;
    ts[kl][nl] = vW[(size_t)(kt * 64 + kl) * 32000 + nt * 64 + nl];
  }
  __syncthreads();
#pragma unroll
  for (int i = 0; i < 16; ++i){
    int idx = tid + i * 256;
    int nl = idx >> 6, kl = idx & 63;
    vWt[(size_t)(nt * 64 + nl) * 768 + kt * 64 + kl] = f2bf(ts[kl][nl]);
  }
}

// ---------------- encoder ----------------
// xw[d][s][n][b] bf16 of emb@Wih + bias   (n = gate*256 + hc)
__global__ __launch_bounds__(256) void k_enc_pre2(const int* __restrict__ src, const float* __restrict__ emb,
                          const float* __restrict__ Wf, const float* __restrict__ bf_,
                          const float* __restrict__ Wb, const float* __restrict__ bb_,
                          u16* __restrict__ xw){
  int d = blockIdx.x / 400, s = blockIdx.x % 400;
  const float* Wih = d ? Wb : Wf; const float* bias = d ? bb_ : bf_;
  __shared__ float es[16][128];
  int tid = threadIdx.x;
  for (int idx = tid; idx < 16 * 128; idx += 256){
    int b = idx >> 7, e = idx & 127;
    es[b][e] = emb[(size_t)src[b * 400 + s] * 128 + e];
  }
  __syncthreads();
  int j = tid;
  float a[4][16];
#pragma unroll
  for (int g = 0; g < 4; ++g){
    float bv = bias[g * 256 + j];
#pragma unroll
    for (int b = 0; b < 16; ++b) a[g][b] = bv;
  }
  for (int e4 = 0; e4 < 32; ++e4){
    float w0[4], w1[4], w2[4], w3[4];
#pragma unroll
    for (int u = 0; u < 4; ++u){
      int e = e4 * 4 + u;
      w0[u] = Wih[(size_t)e * 1024 + j];
      w1[u] = Wih[(size_t)e * 1024 + 256 + j];
      w2[u] = Wih[(size_t)e * 1024 + 512 + j];
      w3[u] = Wih[(size_t)e * 1024 + 768 + j];
    }
#pragma unroll
    for (int b = 0; b < 16; ++b){
      float4 x = *(const float4*)&es[b][e4 * 4];
      a[0][b] += x.x * w0[0] + x.y * w0[1] + x.z * w0[2] + x.w * w0[3];
      a[1][b] += x.x * w1[0] + x.y * w1[1] + x.z * w1[2] + x.w * w1[3];
      a[2][b] += x.x * w2[0] + x.y * w2[1] + x.z * w2[2] + x.w * w2[3];
      a[3][b] += x.x * w3[0] + x.y * w3[1] + x.z * w3[2] + x.w * w3[3];
    }
  }
#pragma unroll
  for (int g = 0; g < 4; ++g){
    u16 tmp[16];
#pragma unroll
    for (int b = 0; b < 16; ++b) tmp[b] = f2bf(a[g][b]);
    uint4* dst = (uint4*)&xw[(((size_t)(d * 400 + s)) * 1024 + g * 256 + j) * 16];
    dst[0] = *(uint4*)&tmp[0];
    dst[1] = *(uint4*)&tmp[8];
  }
}

// Encoder LSTM: 4 blocks (2 dir x 2 hc-halves), 512 thr (8 waves). (unchanged, proven)
__global__ __launch_bounds__(512, 2) void k_enc_lstm4(
    const u16* __restrict__ xw, const u16* __restrict__ wpk,
    u16* __restrict__ enc_out, float* __restrict__ hfin, float* __restrict__ cfin,
    u32* __restrict__ hpub, u32* __restrict__ flags)
{
  const int blk = blockIdx.x;
  const int d = blk >> 1, bp = blk & 1;
  const int tid = threadIdx.x;
  const int w = tid >> 6, lane = tid & 63;
  const int q = lane & 15, r = lane >> 4;
  const int g = w >> 1, sub = w & 1;

  __shared__ u16 hhi[16][264];
  __shared__ u16 hlo[16][264];
  __shared__ float gex[4][16][132];

  for (int idx = tid; idx < 16 * 264; idx += 512){
    hhi[idx / 264][idx % 264] = 0;
    hlo[idx / 264][idx % 264] = 0;
  }

  const u16* wb = wpk + (size_t)d * 1024 * 256;
  int nn[4];
  bf16x8 wreg[4][8];
#pragma unroll
  for (int nt = 0; nt < 4; ++nt){
    nn[nt] = g * 256 + bp * 128 + sub * 64 + nt * 16 + q;
#pragma unroll
    for (int kb = 0; kb < 8; ++kb)
      wreg[nt][kb] = *(const bf16x8*)&wb[(size_t)nn[nt] * 256 + kb * 32 + r * 8];
  }

  const int cb = tid >> 5;
  const int i4 = (tid & 31) * 4;
  float c[4] = {0.f, 0.f, 0.f, 0.f}, hl[4] = {0.f, 0.f, 0.f, 0.f};

  u32* myflag = flags + (d * 2 + bp) * 32;
  u32* rmflag = flags + (d * 2 + (bp ^ 1)) * 32;

  int s0 = d ? 399 : 0;
  ushort4 xv[4];
#pragma unroll
  for (int nt = 0; nt < 4; ++nt)
    xv[nt] = *(const ushort4*)&xw[(((size_t)(d * 400 + s0)) * 1024 + nn[nt]) * 16 + 4 * r];
  __syncthreads();

  for (int it = 0; it < 400; ++it){
    int s = d ? (399 - it) : it;
    f32x4 acc[4];
#pragma unroll
    for (int nt = 0; nt < 4; ++nt){
      acc[nt][0] = bf2f(xv[nt].x); acc[nt][1] = bf2f(xv[nt].y);
      acc[nt][2] = bf2f(xv[nt].z); acc[nt][3] = bf2f(xv[nt].w);
    }
#pragma unroll
    for (int kb = 0; kb < 8; ++kb){
      bf16x8 ah = *(const bf16x8*)&hhi[q][kb * 32 + r * 8];
      bf16x8 al = *(const bf16x8*)&hlo[q][kb * 32 + r * 8];
#pragma unroll
      for (int nt = 0; nt < 4; ++nt){
        acc[nt] = __builtin_amdgcn_mfma_f32_16x16x32_bf16(ah, wreg[nt][kb], acc[nt], 0, 0, 0);
        acc[nt] = __builtin_amdgcn_mfma_f32_16x16x32_bf16(al, wreg[nt][kb], acc[nt], 0, 0, 0);
      }
    }
#pragma unroll
    for (int nt = 0; nt < 4; ++nt)
#pragma unroll
      for (int rg = 0; rg < 4; ++rg)
        gex[g][4 * r + rg][sub * 64 + nt * 16 + q] = acc[nt][rg];
    __syncthreads();

    u32 pk[4];
#pragma unroll
    for (int j = 0; j < 4; ++j){
      int hcl = i4 + j;
      float gi = gex[0][cb][hcl], gf = gex[1][cb][hcl];
      float gg = gex[2][cb][hcl], go = gex[3][cb][hcl];
      float cv = sigm(gf) * c[j] + sigm(gi) * tanh_f(gg);
      float hv = sigm(go) * tanh_f(cv);
      c[j] = cv; hl[j] = hv;
      u16 hi = f2bf(hv);
      u16 lo = f2bf(hv - bf2f(hi));
      pk[j] = ((u32)hi << 16) | lo;
    }
    {
      u64 hi64 = (u64)(pk[0] >> 16) | ((u64)(pk[1] >> 16) << 16)
               | ((u64)(pk[2] >> 16) << 32) | ((u64)(pk[3] >> 16) << 48);
      u64 lo64 = (u64)(pk[0] & 0xffffu) | ((u64)(pk[1] & 0xffffu) << 16)
               | ((u64)(pk[2] & 0xffffu) << 32) | ((u64)(pk[3] & 0xffffu) << 48);
      *(u64*)&hhi[cb][bp * 128 + i4] = hi64;
      *(u64*)&hlo[cb][bp * 128 + i4] = lo64;
      *(u64*)&enc_out[((size_t)cb * 400 + s) * 512 + d * 256 + bp * 128 + i4] = hi64;
    }
    if (it < 399){
      int par = (it + 1) & 1;
      u32* hp_w = hpub + (((size_t)par * 2 + d) * 2 + bp) * 2048;
#pragma unroll
      for (int j = 0; j < 4; ++j)
        __hip_atomic_store(&hp_w[cb * 128 + i4 + j], pk[j], __ATOMIC_RELAXED, __HIP_MEMORY_SCOPE_AGENT);
      int sn = d ? (399 - (it + 1)) : (it + 1);
#pragma unroll
      for (int nt = 0; nt < 4; ++nt)
        xv[nt] = *(const ushort4*)&xw[(((size_t)(d * 400 + sn)) * 1024 + nn[nt]) * 16 + 4 * r];
      __syncthreads();
      if (tid == 0){
        __hip_atomic_store(myflag, (u32)(it + 1), __ATOMIC_RELEASE, __HIP_MEMORY_SCOPE_AGENT);
        while (__hip_atomic_load(rmflag, __ATOMIC_ACQUIRE, __HIP_MEMORY_SCOPE_AGENT) < (u32)(it + 1))
          __builtin_amdgcn_s_sleep(1);
      }
      __syncthreads();
      const u32* hp_r = hpub + (((size_t)par * 2 + d) * 2 + (bp ^ 1)) * 2048;
      u32 rp[4];
#pragma unroll
      for (int j = 0; j < 4; ++j)
        rp[j] = __hip_atomic_load(&hp_r[cb * 128 + i4 + j], __ATOMIC_RELAXED, __HIP_MEMORY_SCOPE_AGENT);
      u64 hi64 = (u64)(rp[0] >> 16) | ((u64)(rp[1] >> 16) << 16)
               | ((u64)(rp[2] >> 16) << 32) | ((u64)(rp[3] >> 16) << 48);
      u64 lo64 = (u64)(rp[0] & 0xffffu) | ((u64)(rp[1] & 0xffffu) << 16)
               | ((u64)(rp[2] & 0xffffu) << 32) | ((u64)(rp[3] & 0xffffu) << 48);
      *(u64*)&hhi[cb][(bp ^ 1) * 128 + i4] = hi64;
      *(u64*)&hlo[cb][(bp ^ 1) * 128 + i4] = lo64;
      __syncthreads();
    }
  }
#pragma unroll
  for (int j = 0; j < 4; ++j){
    hfin[(d * 16 + cb) * 256 + bp * 128 + i4 + j] = hl[j];
    cfin[(d * 16 + cb) * 256 + bp * 128 + i4 + j] = c[j];
  }
}

__global__ void k_reduce(const float* __restrict__ hfin, const float* __restrict__ cfin,
                         const float* __restrict__ rhW, const float* __restrict__ rhb,
                         const float* __restrict__ rcW, const float* __restrict__ rcb,
                         float* __restrict__ h0buf, float* __restrict__ c0buf){
  int b = blockIdx.x, j = threadIdx.x;
  float ah = rhb[j], ac = rcb[j];
  for (int k = 0; k < 256; ++k){
    float hv = hfin[b * 256 + k], cv = cfin[b * 256 + k];
    ah += hv * rhW[k * 256 + j];
    ac += cv * rcW[k * 256 + j];
  }
  for (int k = 0; k < 256; ++k){
    float hv = hfin[(16 + b) * 256 + k], cv = cfin[(16 + b) * 256 + k];
    ah += hv * rhW[(256 + k) * 256 + j];
    ac += cv * rcW[(256 + k) * 256 + j];
  }
  h0buf[b * 256 + j] = tanh_f(ah);
  c0buf[b * 256 + j] = tanh_f(ac);
}

__global__ void k_encfeat(const u16* __restrict__ enc_out, const float* __restrict__ Wh, u16* __restrict__ feat){
  int blk = blockIdx.x; int b = blk / 25; int sc = blk % 25;
  int j = threadIdx.x;
  float acc[16];
#pragma unroll
  for (int i = 0; i < 16; ++i) acc[i] = 0.f;
  const u32* ebase = (const u32*)(enc_out + ((size_t)b * 400 + sc * 16) * 512);
  for (int k2 = 0; k2 < 256; ++k2){
    float wa = Wh[(2 * k2) * 256 + j], wb_ = Wh[(2 * k2 + 1) * 256 + j];
#pragma unroll
    for (int ss = 0; ss < 16; ++ss){
      u32 p = ebase[ss * 256 + k2];
      acc[ss] += bf2f((u16)(p & 0xffff)) * wa + bf2f((u16)(p >> 16)) * wb_;
    }
  }
#pragma unroll
  for (int ss = 0; ss < 16; ++ss)
    feat[((size_t)b * 400 + sc * 16 + ss) * 256 + j] = f2bf(acc[ss]);
}

// ---------------- decoder precompute ----------------
__global__ void k_dec_pre(const int* __restrict__ din, const float* __restrict__ emb,
                          const float* __restrict__ Wih, const float* __restrict__ db,
                          const float* __restrict__ pgW,
                          float4* __restrict__ xwd, float* __restrict__ pg_emb){
  int blk = blockIdx.x; int t = blk / 16, b = blk % 16;
  int j = threadIdx.x;
  int id = din[b * 50 + t];
  const float* er = emb + (size_t)id * 128;
  float a0 = db[j], a1 = db[256 + j], a2 = db[512 + j], a3 = db[768 + j];
  for (int e = 0; e < 128; ++e){
    float x = er[e];
    const float* wr = Wih + (size_t)e * 1024;
    a0 += x * wr[j]; a1 += x * wr[256 + j]; a2 += x * wr[512 + j]; a3 += x * wr[768 + j];
  }
  xwd[(size_t)blk * 256 + j] = make_float4(a0, a1, a2, a3);
  __shared__ float red[256];
  float pe = 0.f;
  if (j < 128) pe = er[j] * pgW[768 + j];
  red[j] = pe; __syncthreads();
  for (int off = 128; off; off >>= 1){ if (j < off) red[j] += red[j + off]; __syncthreads(); }
  if (j == 0) pg_emb[blk] = red[0];
}

// ---------------- persistent decoder loop v2 ----------------
// 16 blocks (1 per batch) x 1024 thr (16 waves). Cell GEMM computed REDUNDANTLY per
// block for all 16 batches via MFMA (A = [ctx;h] hi/lo bf16 in LDS, B = decwt from L2).
// Attention for own batch only. One 16-way ctx exchange + flag sync per step.
__global__ __launch_bounds__(1024, 4) void k_dec_loop2(
    const u16* __restrict__ decwt, const float4* __restrict__ xwd,
    const float* __restrict__ h0buf, const float* __restrict__ c0buf,
    const u16* __restrict__ feat, const u16* __restrict__ enc_out,
    const int* __restrict__ src, const int* __restrict__ src_ext, const int* __restrict__ tgt_ext,
    const float* __restrict__ Ws, const float* __restrict__ Wsb,
    const float* __restrict__ Wc, const float* __restrict__ av_,
    const float* __restrict__ pgW, const float* __restrict__ pg_emb,
    const float* __restrict__ pgb, const float* __restrict__ pgbias,
    u16* __restrict__ Abf, float* __restrict__ pg_all,
    float* __restrict__ cvl_all, float* __restrict__ sct_all,
    u32* __restrict__ cxch, u32* __restrict__ dflags)
{
  const int blk = blockIdx.x;
  const int tid = threadIdx.x;
  const int w = tid >> 6, lane = tid & 63;
  const int q = lane & 15, r = lane >> 4;
  const int g = w >> 2, hcq = w & 3;

  __shared__ u16 a_hi[16][792];     // [ctx(512); h(256)] hi bf16, row pad for banks
  __shared__ u16 a_lo[16][792];
  __shared__ float c_lds[16][256];
  __shared__ float scratch[16 * 516];  // gate-exchange / P2 / P5 partials
  __shared__ float ctx_s[512];
  __shared__ float hf[256];
  __shared__ float hws[256];
  __shared__ float cov[400];
  __shared__ float sc_s[400];
  __shared__ float at_s[400];
  __shared__ float red1[16], red2[16], red3[16];

  // init state (all batches)
  for (int i = tid; i < 16 * 256; i += 1024){
    int b = i >> 8, hc = i & 255;
    float hv = h0buf[i];
    u16 hi = f2bf(hv);
    a_hi[b][512 + hc] = hi;
    a_lo[b][512 + hc] = f2bf(hv - bf2f(hi));
    c_lds[b][hc] = c0buf[i];
    if (b == blk) hf[hc] = hv;
  }
  for (int i = tid; i < 16 * 512; i += 1024){
    int b = i >> 9, j = i & 511;
    a_hi[b][j] = 0; a_lo[b][j] = 0;
  }
  for (int i = tid; i < 400; i += 1024) cov[i] = 0.f;
  float4 wc4 = *(const float4*)&Wc[4 * lane];
  float4 vv4 = *(const float4*)&av_[4 * lane];
  const int n_base = g * 256 + hcq * 64;
  __syncthreads();

  for (int t = 0; t < 50; ++t){
    // ---- cell MFMA: D[batch m][n], wave covers 64 n-cols ----
    f32x4 acc[4];
#pragma unroll
    for (int nt = 0; nt < 4; ++nt){ acc[nt][0]=0.f; acc[nt][1]=0.f; acc[nt][2]=0.f; acc[nt][3]=0.f; }
    for (int kb = 0; kb < 24; ++kb){
      bf16x8 ah = *(const bf16x8*)&a_hi[q][kb * 32 + r * 8];
      bf16x8 al = *(const bf16x8*)&a_lo[q][kb * 32 + r * 8];
#pragma unroll
      for (int nt = 0; nt < 4; ++nt){
        bf16x8 bw = *(const bf16x8*)&decwt[(size_t)(n_base + nt * 16 + q) * 768 + kb * 32 + r * 8];
        acc[nt] = __builtin_amdgcn_mfma_f32_16x16x32_bf16(ah, bw, acc[nt], 0, 0, 0);
        acc[nt] = __builtin_amdgcn_mfma_f32_16x16x32_bf16(al, bw, acc[nt], 0, 0, 0);
      }
    }
    // ---- gate exchange + LSTM combine, two 32KB passes ----
#pragma unroll
    for (int p = 0; p < 2; ++p){
      __syncthreads();
      if ((hcq >> 1) == p){
#pragma unroll
        for (int nt = 0; nt < 4; ++nt){
          int hcp = (hcq & 1) * 64 + nt * 16 + q;
#pragma unroll
          for (int rg = 0; rg < 4; ++rg)
            scratch[(4 * r + rg) * 516 + g * 128 + hcp] = acc[nt][rg];
        }
      }
      __syncthreads();
      {
        int b = tid >> 6, rem = tid & 63;
#pragma unroll
        for (int e = 0; e < 2; ++e){
          int hcp = rem * 2 + e;
          int hc = p * 128 + hcp;
          float gi = scratch[b * 516 + hcp];
          float gf = scratch[b * 516 + 128 + hcp];
          float gg = scratch[b * 516 + 256 + hcp];
          float go = scratch[b * 516 + 384 + hcp];
          float4 xv = xwd[((size_t)t * 16 + b) * 256 + hc];
          float s0 = xv.x + gi, s1 = xv.y + gf, s2 = xv.z + gg, s3 = xv.w + go;
          float cv = sigm(s1) * c_lds[b][hc] + sigm(s0) * tanh_f(s2);
          float hv = sigm(s3) * tanh_f(cv);
          c_lds[b][hc] = cv;
          u16 hi = f2bf(hv);
          a_hi[b][512 + hc] = hi;
          a_lo[b][512 + hc] = f2bf(hv - bf2f(hi));
          if (b == blk){ hf[hc] = hv; Abf[((size_t)t * 16 + b) * 768 + 512 + hc] = hi; }
        }
      }
    }
    __syncthreads();
    // ---- P2: hws = Wsb + h @ Ws (own batch) ----
    {
      int j2 = tid & 255, kq = tid >> 8;
      float a2 = 0.f;
      for (int k = kq * 64; k < kq * 64 + 64; ++k) a2 += hf[k] * Ws[k * 256 + j2];
      scratch[kq * 256 + j2] = a2;
    }
    __syncthreads();
    if (tid < 256) hws[tid] = Wsb[tid] + scratch[tid] + scratch[256 + tid] + scratch[512 + tid] + scratch[768 + tid];
    __syncthreads();
    // ---- P3: scores ----
    {
      float4 hw4 = *(const float4*)&hws[4 * lane];
      for (int s = w; s < 400; s += 16){
        float cvv = cov[s];
        const u16* fp = feat + ((size_t)blk * 400 + s) * 256 + 4 * lane;
        u32 p0 = *(const u32*)fp; u32 p1 = *(const u32*)(fp + 2);
        float f0 = bf2f((u16)(p0 & 0xffff)) + hw4.x + cvv * wc4.x;
        float f1 = bf2f((u16)(p0 >> 16))    + hw4.y + cvv * wc4.y;
        float f2 = bf2f((u16)(p1 & 0xffff)) + hw4.z + cvv * wc4.z;
        float f3 = bf2f((u16)(p1 >> 16))    + hw4.w + cvv * wc4.w;
        float scv = tanh_f(f0) * vv4.x + tanh_f(f1) * vv4.y + tanh_f(f2) * vv4.z + tanh_f(f3) * vv4.w;
#pragma unroll
        for (int m = 32; m; m >>= 1) scv += __shfl_xor(scv, m);
        if (lane == 0) sc_s[s] = (src[blk * 400 + s] == 0) ? -1e9f : scv;
      }
    }
    __syncthreads();
    // ---- P4: softmax ----
    {
      float mv = (tid < 400) ? sc_s[tid] : -1e30f;
#pragma unroll
      for (int m = 32; m; m >>= 1) mv = fmaxf(mv, __shfl_xor(mv, m));
      if (lane == 0) red1[w] = mv;
      __syncthreads();
      float mx = red1[0];
#pragma unroll
      for (int i = 1; i < 16; ++i) mx = fmaxf(mx, red1[i]);
      float ev = 0.f;
      if (tid < 400){ ev = __expf(sc_s[tid] - mx); at_s[tid] = ev; }
#pragma unroll
      for (int m = 32; m; m >>= 1) ev += __shfl_xor(ev, m);
      if (lane == 0) red2[w] = ev;
      __syncthreads();
      float sum = 0.f;
#pragma unroll
      for (int i = 0; i < 16; ++i) sum += red2[i];
      float inv = 1.f / sum;
      if (tid < 400) at_s[tid] *= inv;
    }
    __syncthreads();
    // ---- P5: context ----
    {
      int c2 = (tid & 255) * 2, sh = tid >> 8;
      float a0 = 0.f, a1 = 0.f;
      const u16* eb = enc_out + (size_t)blk * 400 * 512 + c2;
      for (int s = sh * 100; s < sh * 100 + 100; ++s){
        u32 p = *(const u32*)&eb[(size_t)s * 512];
        float av = at_s[s];
        a0 += av * bf2f((u16)(p & 0xffff));
        a1 += av * bf2f((u16)(p >> 16));
      }
      scratch[sh * 1024 + c2] = a0;
      scratch[sh * 1024 + c2 + 1] = a1;
    }
    __syncthreads();
    int par = (t + 1) & 1;
    if (tid < 512){
      float cval = scratch[tid] + scratch[1024 + tid] + scratch[2048 + tid] + scratch[3072 + tid];
      ctx_s[tid] = cval;
      Abf[((size_t)t * 16 + blk) * 768 + tid] = f2bf(cval);
      if (t < 49){
        u32 bits; __builtin_memcpy(&bits, &cval, 4);
        __hip_atomic_store(&cxch[((size_t)par * 16 + blk) * 512 + tid], bits, __ATOMIC_RELAXED, __HIP_MEMORY_SCOPE_AGENT);
      }
    }
    __syncthreads();   // drains cxch stores (vmcnt) block-wide
    if (t < 49 && tid == 0)
      __hip_atomic_store(&dflags[blk * 32], (u32)(t + 1), __ATOMIC_RELEASE, __HIP_MEMORY_SCOPE_AGENT);
    // ---- P6: coverage/pgen (overlaps other blocks' progress) ----
    {
      float clp = 0.f, scp = 0.f, pgp = 0.f;
      int tg = tgt_ext[blk * 50 + t];
      if (tid < 400){
        float a = at_s[tid];
        float cvv = cov[tid];
        clp = fminf(a, cvv);
        cov[tid] = cvv + a;
        if (src_ext[blk * 400 + tid] == tg) scp = a;
      }
      if (tid < 512) pgp = ctx_s[tid] * pgW[tid];
      else if (tid < 768) pgp = hf[tid - 512] * pgW[tid];
#pragma unroll
      for (int m = 32; m; m >>= 1){
        clp += __shfl_xor(clp, m);
        scp += __shfl_xor(scp, m);
        pgp += __shfl_xor(pgp, m);
      }
      if (lane == 0){ red1[w] = clp; red2[w] = scp; red3[w] = pgp; }
      __syncthreads();
      if (tid == 0){
        float cl = 0.f, sc2 = 0.f, pgs = 0.f;
#pragma unroll
        for (int i = 0; i < 16; ++i){ cl += red1[i]; sc2 += red2[i]; pgs += red3[i]; }
        float pg = sigm(pgs + pg_emb[t * 16 + blk] + pgb[0] + pgbias[0]);
        pg = fminf(fmaxf(pg, 0.1f), 0.9f);
        pg_all[t * 16 + blk] = pg; cvl_all[t * 16 + blk] = cl; sct_all[t * 16 + blk] = sc2;
      }
    }
    __syncthreads();
    // ---- ctx exchange: wait all, read all 16 batches ----
    if (t < 49){
      if (tid < 64){
        int i = tid & 15;
        while (__hip_atomic_load(&dflags[i * 32], __ATOMIC_ACQUIRE, __HIP_MEMORY_SCOPE_AGENT) < (u32)(t + 1))
          __builtin_amdgcn_s_sleep(1);
      }
      __syncthreads();
      for (int i = tid; i < 16 * 512; i += 1024){
        int b = i >> 9, j = i & 511;
        u32 bits = __hip_atomic_load(&cxch[((size_t)par * 16 + b) * 512 + j], __ATOMIC_RELAXED, __HIP_MEMORY_SCOPE_AGENT);
        float cval; __builtin_memcpy(&cval, &bits, 4);
        u16 hi = f2bf(cval);
        a_hi[b][j] = hi;
        a_lo[b][j] = f2bf(cval - bf2f(hi));
      }
      __syncthreads();
    }
  }
}

// ---------------- batched vocab ----------------
__global__ __launch_bounds__(256) void k_vgemm(const u16* __restrict__ Abf, const u16* __restrict__ vWt,
    const float* __restrict__ vb, const int* __restrict__ tgt_ext,
    float* __restrict__ mpart2, float* __restrict__ spart2, float* __restrict__ ltgt_all){
  int nslab = blockIdx.x, mslab = blockIdx.y;
  int tid = threadIdx.x;
  int w = tid >> 6, lane = tid & 63, q = lane & 15, r = lane >> 4;
  int m0 = mslab * 80;
  int n0w = nslab * 256 + w * 64;
  f32x4 acc[5][4];
#pragma unroll
  for (int mt = 0; mt < 5; ++mt)
#pragma unroll
    for (int nt = 0; nt < 4; ++nt){ acc[mt][nt][0]=0.f; acc[mt][nt][1]=0.f; acc[mt][nt][2]=0.f; acc[mt][nt][3]=0.f; }

  for (int kb = 0; kb < 24; ++kb){
    bf16x8 bfrag[4], afrag[5];
#pragma unroll
    for (int nt = 0; nt < 4; ++nt)
      bfrag[nt] = *(const bf16x8*)&vWt[(size_t)(n0w + nt * 16 + q) * 768 + kb * 32 + r * 8];
#pragma unroll
    for (int mt = 0; mt < 5; ++mt)
      afrag[mt] = *(const bf16x8*)&Abf[(size_t)(m0 + mt * 16 + q) * 768 + kb * 32 + r * 8];
#pragma unroll
    for (int mt = 0; mt < 5; ++mt)
#pragma unroll
      for (int nt = 0; nt < 4; ++nt)
        acc[mt][nt] = __builtin_amdgcn_mfma_f32_16x16x32_bf16(afrag[mt], bfrag[nt], acc[mt][nt], 0, 0, 0);
  }
  float vbc[4];
#pragma unroll
  for (int nt = 0; nt < 4; ++nt) vbc[nt] = vb[n0w + nt * 16 + q];

  __shared__ float pm[4][80], ps[4][80];
#pragma unroll
  for (int mt = 0; mt < 5; ++mt){
#pragma unroll
    for (int rg = 0; rg < 4; ++rg){
      int row = m0 + mt * 16 + 4 * r + rg;
      int tg = tgt_ext[(row & 15) * 50 + (row >> 4)];
      float v0 = acc[mt][0][rg] + vbc[0];
      float v1 = acc[mt][1][rg] + vbc[1];
      float v2 = acc[mt][2][rg] + vbc[2];
      float v3 = acc[mt][3][rg] + vbc[3];
      if (n0w + 0 * 16 + q == tg) ltgt_all[row] = v0;
      if (n0w + 1 * 16 + q == tg) ltgt_all[row] = v1;
      if (n0w + 2 * 16 + q == tg) ltgt_all[row] = v2;
      if (n0w + 3 * 16 + q == tg) ltgt_all[row] = v3;
      float mx = fmaxf(fmaxf(v0, v1), fmaxf(v2, v3));
#pragma unroll
      for (int mk = 1; mk < 16; mk <<= 1) mx = fmaxf(mx, __shfl_xor(mx, mk));
      float se = __expf(v0 - mx) + __expf(v1 - mx) + __expf(v2 - mx) + __expf(v3 - mx);
#pragma unroll
      for (int mk = 1; mk < 16; mk <<= 1) se += __shfl_xor(se, mk);
      if (q == 0){ pm[w][mt * 16 + 4 * r + rg] = mx; ps[w][mt * 16 + 4 * r + rg] = se; }
    }
  }
  __syncthreads();
  if (tid < 80){
    float m = pm[0][tid], s = ps[0][tid];
#pragma unroll
    for (int w2 = 1; w2 < 4; ++w2){
      float om = pm[w2][tid], os = ps[w2][tid];
      float M = fmaxf(m, om);
      s = s * __expf(m - M) + os * __expf(om - M);
      m = M;
    }
    mpart2[(size_t)(m0 + tid) * 125 + nslab] = m;
    spart2[(size_t)(m0 + tid) * 125 + nslab] = s;
  }
}

__global__ void k_comb2(const float* __restrict__ mpart2, const float* __restrict__ spart2,
                        const float* __restrict__ ltgt_all, const float* __restrict__ pg_all,
                        const float* __restrict__ cvl_all, const float* __restrict__ sct_all,
                        const int* __restrict__ tgt_ext, const float* __restrict__ lam,
                        float* __restrict__ loss_g, float* __restrict__ valid_g){
  int t = blockIdx.x; int tid = threadIdx.x;
  int b = tid >> 4, l16 = tid & 15;
  int row = t * 16 + b;
  float m = -1e30f, s = 0.f;
  for (int i = l16; i < 125; i += 16){
    float om = mpart2[(size_t)row * 125 + i], os = spart2[(size_t)row * 125 + i];
    float M = fmaxf(m, om);
    s = s * __expf(m - M) + os * __expf(om - M);
    m = M;
  }
#pragma unroll
  for (int mk = 1; mk < 16; mk <<= 1){
    float om = __shfl_xor(m, mk), os = __shfl_xor(s, mk);
    float M = fmaxf(m, om);
    s = s * __expf(m - M) + os * __expf(om - M);
    m = M;
  }
  if (l16 == 0){
    int tg = tgt_ext[b * 50 + t];
    float pv = (tg < 32000) ? (__expf(ltgt_all[row] - m) / s) : 0.f;
    float pg = pg_all[row];
    float pf = pg * pv + (1.f - pg) * sct_all[row];
    float sl = -__logf(pf + 1e-12f);
    float msk = (tg != 0) ? 1.f : 0.f;
    loss_g[row] = (sl + lam[0] * cvl_all[row]) * msk;
    valid_g[row] = msk;
  }
}

__global__ void k_final(const float* __restrict__ loss_g, const float* __restrict__ valid_g, float* __restrict__ out){
  __shared__ float r1[256], r2[256];
  int tid = threadIdx.x;
  float a = 0.f, v = 0.f;
  for (int i = tid; i < 800; i += 256){ a += loss_g[i]; v += valid_g[i]; }
  r1[tid] = a; r2[tid] = v; __syncthreads();
  for (int off = 128; off; off >>= 1){
    if (tid < off){ r1[tid] += r1[tid + off]; r2[tid] += r2[tid + off]; }
    __syncthreads();
  }
  if (tid == 0) out[0] = r1[0] / fmaxf(r2[0], 1.f);
}

extern "C" void kernel_launch(void* const* d_in, const int* in_sizes, int n_in,
                              void* d_out, int out_size, void* d_ws, size_t ws_size,
                              hipStream_t stream){
  const int*   src     = (const int*)  d_in[0];
  const int*   src_ext = (const int*)  d_in[1];
  const int*   dec_in  = (const int*)  d_in[2];
  const int*   tgt_ext = (const int*)  d_in[3];
  const float* enc_emb = (const float*)d_in[5];
  const float* eWihF   = (const float*)d_in[6];
  const float* eWhhF   = (const float*)d_in[7];
  const float* ebF     = (const float*)d_in[8];
  const float* eWihB   = (const float*)d_in[9];
  const float* eWhhB   = (const float*)d_in[10];
  const float* ebB     = (const float*)d_in[11];
  const float* rhW     = (const float*)d_in[12];
  const float* rhb     = (const float*)d_in[13];
  const float* rcW     = (const float*)d_in[14];
  const float* rcb     = (const float*)d_in[15];
  const float* dec_emb = (const float*)d_in[16];
  const float* dWih    = (const float*)d_in[17];
  const float* dWhh    = (const float*)d_in[18];
  const float* db_     = (const float*)d_in[19];
  const float* aWh     = (const float*)d_in[20];
  const float* aWs     = (const float*)d_in[21];
  const float* aWsb    = (const float*)d_in[22];
  const float* aWc     = (const float*)d_in[23];
  const float* av      = (const float*)d_in[24];
  const float* pgW     = (const float*)d_in[25];
  const float* pgb     = (const float*)d_in[26];
  const float* vW      = (const float*)d_in[27];
  const float* vb      = (const float*)d_in[28];
  const float* lam     = (const float*)d_in[29];
  const float* pgbias  = (const float*)d_in[30];
  (void)in_sizes; (void)n_in; (void)out_size; (void)ws_size;

  char* w = (char*)d_ws;
  size_t off = 0;
  auto alloc = [&](size_t bytes) -> char* {
    char* p = w + off; off += (bytes + 255) & ~(size_t)255; return p;
  };
  u16*     xw      = (u16*)    alloc(2ull * 400 * 1024 * 16 * 2);
  u16*     whhp    = (u16*)    alloc(2ull * 1024 * 256 * 2);
  u16*     decwt   = (u16*)    alloc(1024ull * 768 * 2);
  u16*     enc_out = (u16*)    alloc(16ull * 400 * 512 * 2);
  u16*     feat    = (u16*)    alloc(16ull * 400 * 256 * 2);
  float*   hfin    = (float*)  alloc(2 * 16 * 256 * 4);
  float*   cfin    = (float*)  alloc(2 * 16 * 256 * 4);
  float*   h0buf   = (float*)  alloc(16 * 256 * 4);
  float*   c0buf   = (float*)  alloc(16 * 256 * 4);
  float4*  xwd     = (float4*) alloc(50ull * 16 * 256 * 16);
  float*   pg_emb  = (float*)  alloc(800 * 4);
  u32*     hpub    = (u32*)    alloc(8ull * 2048 * 4);
  u32*     flags   = (u32*)    alloc(4 * 32 * 4);
  u32*     cxch    = (u32*)    alloc(2ull * 16 * 512 * 4);   // 64KB ctx exchange
  u32*     dflags  = (u32*)    alloc(16 * 32 * 4);           // 2KB decoder flags
  u16*     Abf     = (u16*)    alloc(800ull * 768 * 2);
  float*   ltgt_all= (float*)  alloc(800 * 4);
  float*   pg_all  = (float*)  alloc(800 * 4);
  float*   cvl_all = (float*)  alloc(800 * 4);
  float*   sct_all = (float*)  alloc(800 * 4);
  float*   loss_g  = (float*)  alloc(800 * 4);
  float*   valid_g = (float*)  alloc(800 * 4);
  float*   mpart2  = (float*)  alloc(800ull * 125 * 4);
  float*   spart2  = (float*)  alloc(800ull * 125 * 4);
  u16*     vWt     = (u16*)    alloc(32000ull * 768 * 2);

  hipMemsetAsync(flags, 0, 4 * 32 * 4, stream);
  hipMemsetAsync(dflags, 0, 16 * 32 * 4, stream);

  hipLaunchKernelGGL(k_pack_whh2,  dim3(2048),  dim3(256), 0, stream, eWhhF, eWhhB, whhp);
  hipLaunchKernelGGL(k_pack_decwt, dim3(1024),  dim3(256), 0, stream, dWih, dWhh, decwt);
  hipLaunchKernelGGL(k_pack_vwt,   dim3(500, 12), dim3(256), 0, stream, vW, vWt);
  hipLaunchKernelGGL(k_enc_pre2,   dim3(800),   dim3(256), 0, stream, src, enc_emb, eWihF, ebF, eWihB, ebB, xw);
  hipLaunchKernelGGL(k_dec_pre,    dim3(800),   dim3(256), 0, stream, dec_in, dec_emb, dWih, db_, pgW, xwd, pg_emb);
  hipLaunchKernelGGL(k_enc_lstm4,  dim3(4),     dim3(512), 0, stream, xw, whhp, enc_out, hfin, cfin, hpub, flags);
  hipLaunchKernelGGL(k_reduce,     dim3(16),    dim3(256), 0, stream, hfin, cfin, rhW, rhb, rcW, rcb, h0buf, c0buf);
  hipLaunchKernelGGL(k_encfeat,    dim3(400),   dim3(256), 0, stream, enc_out, aWh, feat);
  hipLaunchKernelGGL(k_dec_loop2,  dim3(16),    dim3(1024), 0, stream,
                     decwt, xwd, h0buf, c0buf, feat, enc_out, src, src_ext, tgt_ext,
                     aWs, aWsb, aWc, av, pgW, pg_emb, pgb, pgbias,
                     Abf, pg_all, cvl_all, sct_all, cxch, dflags);
  hipLaunchKernelGGL(k_vgemm,  dim3(125, 10), dim3(256), 0, stream, Abf, vWt, vb, tgt_ext, mpart2, spart2, ltgt_all);
  hipLaunchKernelGGL(k_comb2,  dim3(50), dim3(256), 0, stream, mpart2, spart2, ltgt_all,
                     pg_all, cvl_all, sct_all, tgt_ext, lam, loss_g, valid_g);
  hipLaunchKernelGGL(k_final, dim3(1), dim3(256), 0, stream, loss_g, valid_g, (float*)d_out);
}

// Round 8
// 7823.381 us; speedup vs baseline: 1.0709x; 1.0709x over previous
//
#include <hip/hip_runtime.h>
#include <math.h>

typedef unsigned short u16;
typedef unsigned int   u32;
typedef unsigned long long u64;
typedef __attribute__((ext_vector_type(8))) short bf16x8;
typedef __attribute__((ext_vector_type(4))) float f32x4;

#define DEVI static __device__ __forceinline__

DEVI float bf2f(u16 u){ u32 x = ((u32)u) << 16; float f; __builtin_memcpy(&f, &x, 4); return f; }
DEVI u16 f2bf(float f){ u32 x; __builtin_memcpy(&x, &f, 4); u32 r = (x + 0x7fffu + ((x >> 16) & 1u)) >> 16; return (u16)r; }
DEVI float sigm(float x){ return 1.f / (1.f + __expf(-x)); }
DEVI float tanh_f(float x){ float e = __expf(2.f * x); return 1.f - 2.f / (e + 1.f); }

// ---------------- pack kernels ----------------
__global__ void k_pack_whh2(const float* __restrict__ Wf, const float* __restrict__ Wb, u16* __restrict__ out){
  int blk = blockIdx.x;             // 2*1024
  int d = blk >> 10, n = blk & 1023;
  const float* W = d ? Wb : Wf;
  int k = threadIdx.x;
  out[((size_t)d * 1024 + n) * 256 + k] = f2bf(W[(size_t)k * 1024 + n]);
}

// decoder weights transposed: decwt[n][k], n = gate*256+hc, k<512 -> Wih row 128+k, else Whh row k-512
__global__ void k_pack_decwt(const float* __restrict__ Wih, const float* __restrict__ Whh, u16* __restrict__ out){
  int n = blockIdx.x;               // 1024
  for (int k = threadIdx.x; k < 768; k += 256){
    const float* row = (k < 512) ? (Wih + (size_t)(128 + k) * 1024) : (Whh + (size_t)(k - 512) * 1024);
    out[(size_t)n * 768 + k] = f2bf(row[n]);
  }
}

// vW [768][32000] f32 -> vWt [32000][768] bf16
__global__ __launch_bounds__(256) void k_pack_vwt(const float* __restrict__ vW, u16* __restrict__ vWt){
  __shared__ float ts[64][65];
  int nt = blockIdx.x, kt = blockIdx.y;   // 500 x 12
  int tid = threadIdx.x;
#pragma unroll
  for (int i = 0; i < 16; ++i){
    int idx = tid + i * 256;
    int kl = idx >> 6, nl = idx & 63;
    ts[kl][nl] = vW[(size_t)(kt * 64 + kl) * 32000 + nt * 64 + nl];
  }
  __syncthreads();
#pragma unroll
  for (int i = 0; i < 16; ++i){
    int idx = tid + i * 256;
    int nl = idx >> 6, kl = idx & 63;
    vWt[(size_t)(nt * 64 + nl) * 768 + kt * 64 + kl] = f2bf(ts[kl][nl]);
  }
}

// ---------------- encoder ----------------
// xw[d][s][n][b] bf16 of emb@Wih + bias   (n = gate*256 + hc)
__global__ __launch_bounds__(256) void k_enc_pre2(const int* __restrict__ src, const float* __restrict__ emb,
                          const float* __restrict__ Wf, const float* __restrict__ bf_,
                          const float* __restrict__ Wb, const float* __restrict__ bb_,
                          u16* __restrict__ xw){
  int d = blockIdx.x / 400, s = blockIdx.x % 400;
  const float* Wih = d ? Wb : Wf; const float* bias = d ? bb_ : bf_;
  __shared__ float es[16][128];
  int tid = threadIdx.x;
  for (int idx = tid; idx < 16 * 128; idx += 256){
    int b = idx >> 7, e = idx & 127;
    es[b][e] = emb[(size_t)src[b * 400 + s] * 128 + e];
  }
  __syncthreads();
  int j = tid;
  float a[4][16];
#pragma unroll
  for (int g = 0; g < 4; ++g){
    float bv = bias[g * 256 + j];
#pragma unroll
    for (int b = 0; b < 16; ++b) a[g][b] = bv;
  }
  for (int e4 = 0; e4 < 32; ++e4){
    float w0[4], w1[4], w2[4], w3[4];
#pragma unroll
    for (int u = 0; u < 4; ++u){
      int e = e4 * 4 + u;
      w0[u] = Wih[(size_t)e * 1024 + j];
      w1[u] = Wih[(size_t)e * 1024 + 256 + j];
      w2[u] = Wih[(size_t)e * 1024 + 512 + j];
      w3[u] = Wih[(size_t)e * 1024 + 768 + j];
    }
#pragma unroll
    for (int b = 0; b < 16; ++b){
      float4 x = *(const float4*)&es[b][e4 * 4];
      a[0][b] += x.x * w0[0] + x.y * w0[1] + x.z * w0[2] + x.w * w0[3];
      a[1][b] += x.x * w1[0] + x.y * w1[1] + x.z * w1[2] + x.w * w1[3];
      a[2][b] += x.x * w2[0] + x.y * w2[1] + x.z * w2[2] + x.w * w2[3];
      a[3][b] += x.x * w3[0] + x.y * w3[1] + x.z * w3[2] + x.w * w3[3];
    }
  }
#pragma unroll
  for (int g = 0; g < 4; ++g){
    u16 tmp[16];
#pragma unroll
    for (int b = 0; b < 16; ++b) tmp[b] = f2bf(a[g][b]);
    uint4* dst = (uint4*)&xw[(((size_t)(d * 400 + s)) * 1024 + g * 256 + j) * 16];
    dst[0] = *(uint4*)&tmp[0];
    dst[1] = *(uint4*)&tmp[8];
  }
}

// Encoder LSTM: 4 blocks (2 dir x 2 hc-halves), 512 thr (8 waves). (unchanged, proven)
__global__ __launch_bounds__(512, 2) void k_enc_lstm4(
    const u16* __restrict__ xw, const u16* __restrict__ wpk,
    u16* __restrict__ enc_out, float* __restrict__ hfin, float* __restrict__ cfin,
    u32* __restrict__ hpub, u32* __restrict__ flags)
{
  const int blk = blockIdx.x;
  const int d = blk >> 1, bp = blk & 1;
  const int tid = threadIdx.x;
  const int w = tid >> 6, lane = tid & 63;
  const int q = lane & 15, r = lane >> 4;
  const int g = w >> 1, sub = w & 1;

  __shared__ u16 hhi[16][264];
  __shared__ u16 hlo[16][264];
  __shared__ float gex[4][16][132];

  for (int idx = tid; idx < 16 * 264; idx += 512){
    hhi[idx / 264][idx % 264] = 0;
    hlo[idx / 264][idx % 264] = 0;
  }

  const u16* wb = wpk + (size_t)d * 1024 * 256;
  int nn[4];
  bf16x8 wreg[4][8];
#pragma unroll
  for (int nt = 0; nt < 4; ++nt){
    nn[nt] = g * 256 + bp * 128 + sub * 64 + nt * 16 + q;
#pragma unroll
    for (int kb = 0; kb < 8; ++kb)
      wreg[nt][kb] = *(const bf16x8*)&wb[(size_t)nn[nt] * 256 + kb * 32 + r * 8];
  }

  const int cb = tid >> 5;
  const int i4 = (tid & 31) * 4;
  float c[4] = {0.f, 0.f, 0.f, 0.f}, hl[4] = {0.f, 0.f, 0.f, 0.f};

  u32* myflag = flags + (d * 2 + bp) * 32;
  u32* rmflag = flags + (d * 2 + (bp ^ 1)) * 32;

  int s0 = d ? 399 : 0;
  ushort4 xv[4];
#pragma unroll
  for (int nt = 0; nt < 4; ++nt)
    xv[nt] = *(const ushort4*)&xw[(((size_t)(d * 400 + s0)) * 1024 + nn[nt]) * 16 + 4 * r];
  __syncthreads();

  for (int it = 0; it < 400; ++it){
    int s = d ? (399 - it) : it;
    f32x4 acc[4];
#pragma unroll
    for (int nt = 0; nt < 4; ++nt){
      acc[nt][0] = bf2f(xv[nt].x); acc[nt][1] = bf2f(xv[nt].y);
      acc[nt][2] = bf2f(xv[nt].z); acc[nt][3] = bf2f(xv[nt].w);
    }
#pragma unroll
    for (int kb = 0; kb < 8; ++kb){
      bf16x8 ah = *(const bf16x8*)&hhi[q][kb * 32 + r * 8];
      bf16x8 al = *(const bf16x8*)&hlo[q][kb * 32 + r * 8];
#pragma unroll
      for (int nt = 0; nt < 4; ++nt){
        acc[nt] = __builtin_amdgcn_mfma_f32_16x16x32_bf16(ah, wreg[nt][kb], acc[nt], 0, 0, 0);
        acc[nt] = __builtin_amdgcn_mfma_f32_16x16x32_bf16(al, wreg[nt][kb], acc[nt], 0, 0, 0);
      }
    }
#pragma unroll
    for (int nt = 0; nt < 4; ++nt)
#pragma unroll
      for (int rg = 0; rg < 4; ++rg)
        gex[g][4 * r + rg][sub * 64 + nt * 16 + q] = acc[nt][rg];
    __syncthreads();

    u32 pk[4];
#pragma unroll
    for (int j = 0; j < 4; ++j){
      int hcl = i4 + j;
      float gi = gex[0][cb][hcl], gf = gex[1][cb][hcl];
      float gg = gex[2][cb][hcl], go = gex[3][cb][hcl];
      float cv = sigm(gf) * c[j] + sigm(gi) * tanh_f(gg);
      float hv = sigm(go) * tanh_f(cv);
      c[j] = cv; hl[j] = hv;
      u16 hi = f2bf(hv);
      u16 lo = f2bf(hv - bf2f(hi));
      pk[j] = ((u32)hi << 16) | lo;
    }
    {
      u64 hi64 = (u64)(pk[0] >> 16) | ((u64)(pk[1] >> 16) << 16)
               | ((u64)(pk[2] >> 16) << 32) | ((u64)(pk[3] >> 16) << 48);
      u64 lo64 = (u64)(pk[0] & 0xffffu) | ((u64)(pk[1] & 0xffffu) << 16)
               | ((u64)(pk[2] & 0xffffu) << 32) | ((u64)(pk[3] & 0xffffu) << 48);
      *(u64*)&hhi[cb][bp * 128 + i4] = hi64;
      *(u64*)&hlo[cb][bp * 128 + i4] = lo64;
      *(u64*)&enc_out[((size_t)cb * 400 + s) * 512 + d * 256 + bp * 128 + i4] = hi64;
    }
    if (it < 399){
      int par = (it + 1) & 1;
      u32* hp_w = hpub + (((size_t)par * 2 + d) * 2 + bp) * 2048;
#pragma unroll
      for (int j = 0; j < 4; ++j)
        __hip_atomic_store(&hp_w[cb * 128 + i4 + j], pk[j], __ATOMIC_RELAXED, __HIP_MEMORY_SCOPE_AGENT);
      int sn = d ? (399 - (it + 1)) : (it + 1);
#pragma unroll
      for (int nt = 0; nt < 4; ++nt)
        xv[nt] = *(const ushort4*)&xw[(((size_t)(d * 400 + sn)) * 1024 + nn[nt]) * 16 + 4 * r];
      __syncthreads();
      if (tid == 0){
        __hip_atomic_store(myflag, (u32)(it + 1), __ATOMIC_RELEASE, __HIP_MEMORY_SCOPE_AGENT);
        while (__hip_atomic_load(rmflag, __ATOMIC_ACQUIRE, __HIP_MEMORY_SCOPE_AGENT) < (u32)(it + 1))
          __builtin_amdgcn_s_sleep(1);
      }
      __syncthreads();
      const u32* hp_r = hpub + (((size_t)par * 2 + d) * 2 + (bp ^ 1)) * 2048;
      u32 rp[4];
#pragma unroll
      for (int j = 0; j < 4; ++j)
        rp[j] = __hip_atomic_load(&hp_r[cb * 128 + i4 + j], __ATOMIC_RELAXED, __HIP_MEMORY_SCOPE_AGENT);
      u64 hi64 = (u64)(rp[0] >> 16) | ((u64)(rp[1] >> 16) << 16)
               | ((u64)(rp[2] >> 16) << 32) | ((u64)(rp[3] >> 16) << 48);
      u64 lo64 = (u64)(rp[0] & 0xffffu) | ((u64)(rp[1] & 0xffffu) << 16)
               | ((u64)(rp[2] & 0xffffu) << 32) | ((u64)(rp[3] & 0xffffu) << 48);
      *(u64*)&hhi[cb][(bp ^ 1) * 128 + i4] = hi64;
      *(u64*)&hlo[cb][(bp ^ 1) * 128 + i4] = lo64;
      __syncthreads();
    }
  }
#pragma unroll
  for (int j = 0; j < 4; ++j){
    hfin[(d * 16 + cb) * 256 + bp * 128 + i4 + j] = hl[j];
    cfin[(d * 16 + cb) * 256 + bp * 128 + i4 + j] = c[j];
  }
}

__global__ void k_reduce(const float* __restrict__ hfin, const float* __restrict__ cfin,
                         const float* __restrict__ rhW, const float* __restrict__ rhb,
                         const float* __restrict__ rcW, const float* __restrict__ rcb,
                         float* __restrict__ h0buf, float* __restrict__ c0buf){
  int b = blockIdx.x, j = threadIdx.x;
  float ah = rhb[j], ac = rcb[j];
  for (int k = 0; k < 256; ++k){
    float hv = hfin[b * 256 + k], cv = cfin[b * 256 + k];
    ah += hv * rhW[k * 256 + j];
    ac += cv * rcW[k * 256 + j];
  }
  for (int k = 0; k < 256; ++k){
    float hv = hfin[(16 + b) * 256 + k], cv = cfin[(16 + b) * 256 + k];
    ah += hv * rhW[(256 + k) * 256 + j];
    ac += cv * rcW[(256 + k) * 256 + j];
  }
  h0buf[b * 256 + j] = tanh_f(ah);
  c0buf[b * 256 + j] = tanh_f(ac);
}

__global__ void k_encfeat(const u16* __restrict__ enc_out, const float* __restrict__ Wh, u16* __restrict__ feat){
  int blk = blockIdx.x; int b = blk / 25; int sc = blk % 25;
  int j = threadIdx.x;
  float acc[16];
#pragma unroll
  for (int i = 0; i < 16; ++i) acc[i] = 0.f;
  const u32* ebase = (const u32*)(enc_out + ((size_t)b * 400 + sc * 16) * 512);
  for (int k2 = 0; k2 < 256; ++k2){
    float wa = Wh[(2 * k2) * 256 + j], wb_ = Wh[(2 * k2 + 1) * 256 + j];
#pragma unroll
    for (int ss = 0; ss < 16; ++ss){
      u32 p = ebase[ss * 256 + k2];
      acc[ss] += bf2f((u16)(p & 0xffff)) * wa + bf2f((u16)(p >> 16)) * wb_;
    }
  }
#pragma unroll
  for (int ss = 0; ss < 16; ++ss)
    feat[((size_t)b * 400 + sc * 16 + ss) * 256 + j] = f2bf(acc[ss]);
}

// ---------------- decoder precompute ----------------
__global__ void k_dec_pre(const int* __restrict__ din, const float* __restrict__ emb,
                          const float* __restrict__ Wih, const float* __restrict__ db,
                          const float* __restrict__ pgW,
                          float4* __restrict__ xwd, float* __restrict__ pg_emb){
  int blk = blockIdx.x; int t = blk / 16, b = blk % 16;
  int j = threadIdx.x;
  int id = din[b * 50 + t];
  const float* er = emb + (size_t)id * 128;
  float a0 = db[j], a1 = db[256 + j], a2 = db[512 + j], a3 = db[768 + j];
  for (int e = 0; e < 128; ++e){
    float x = er[e];
    const float* wr = Wih + (size_t)e * 1024;
    a0 += x * wr[j]; a1 += x * wr[256 + j]; a2 += x * wr[512 + j]; a3 += x * wr[768 + j];
  }
  xwd[(size_t)blk * 256 + j] = make_float4(a0, a1, a2, a3);
  __shared__ float red[256];
  float pe = 0.f;
  if (j < 128) pe = er[j] * pgW[768 + j];
  red[j] = pe; __syncthreads();
  for (int off = 128; off; off >>= 1){ if (j < off) red[j] += red[j + off]; __syncthreads(); }
  if (j == 0) pg_emb[blk] = red[0];
}

// ---------------- persistent decoder loop v3 ----------------
// 16 blocks (1 per batch) x 1024 thr (16 waves). NO cross-block communication.
// Cell gates for OWN batch via MFMA with A rows replicated (all 16 M-rows = own [ctx;h]
// hi/lo bf16 from LDS). Wave w owns 64 gate-cols; decwt streamed from XCD L2 (hot).
__global__ __launch_bounds__(1024, 1) void k_dec_loop3(
    const u16* __restrict__ decwt, const float4* __restrict__ xwd,
    const float* __restrict__ h0buf, const float* __restrict__ c0buf,
    const u16* __restrict__ feat, const u16* __restrict__ enc_out,
    const int* __restrict__ src, const int* __restrict__ src_ext, const int* __restrict__ tgt_ext,
    const float* __restrict__ Ws, const float* __restrict__ Wsb,
    const float* __restrict__ Wc, const float* __restrict__ av_,
    const float* __restrict__ pgW, const float* __restrict__ pg_emb,
    const float* __restrict__ pgb, const float* __restrict__ pgbias,
    u16* __restrict__ Abf, float* __restrict__ pg_all,
    float* __restrict__ cvl_all, float* __restrict__ sct_all)
{
  const int blk = blockIdx.x;
  const int tid = threadIdx.x;
  const int w = tid >> 6, lane = tid & 63;
  const int r = lane >> 4;

  __shared__ u16 a_hi[800];         // [ctx(512); h(256)] hi bf16 (own batch)
  __shared__ u16 a_lo[800];
  __shared__ float c_lds[256];
  __shared__ float gates[1024];
  __shared__ float scratch[4096];
  __shared__ float ctx_s[512];
  __shared__ float hf[256];
  __shared__ float hws[256];
  __shared__ float cov[400];
  __shared__ float sc_s[400];
  __shared__ float at_s[400];
  __shared__ float red1[16], red2[16], red3[16];

  // init own-batch state
  if (tid < 256){
    float hv = h0buf[blk * 256 + tid];
    u16 hi = f2bf(hv);
    a_hi[512 + tid] = hi;
    a_lo[512 + tid] = f2bf(hv - bf2f(hi));
    c_lds[tid] = c0buf[blk * 256 + tid];
    hf[tid] = hv;
  }
  for (int i = tid; i < 512; i += 1024){ a_hi[i] = 0; a_lo[i] = 0; }
  for (int i = tid; i < 400; i += 1024) cov[i] = 0.f;
  float4 wc4 = *(const float4*)&Wc[4 * lane];
  float4 vv4 = *(const float4*)&av_[4 * lane];
  const int q = lane & 15;
  const u16* wbase = decwt + (size_t)(w * 64 + q) * 768;
  __syncthreads();

  for (int t = 0; t < 50; ++t){
    // ---- cell MFMA: gates[w*64 .. w*64+63] for own batch (A rows replicated) ----
    {
      f32x4 acc0 = {0.f,0.f,0.f,0.f}, acc1 = {0.f,0.f,0.f,0.f};
      f32x4 acc2 = {0.f,0.f,0.f,0.f}, acc3 = {0.f,0.f,0.f,0.f};
      for (int kb = 0; kb < 24; ++kb){
        bf16x8 ah = *(const bf16x8*)&a_hi[kb * 32 + r * 8];
        bf16x8 al = *(const bf16x8*)&a_lo[kb * 32 + r * 8];
        bf16x8 b0 = *(const bf16x8*)&wbase[0 * 16 * 768 + kb * 32 + r * 8];
        bf16x8 b1 = *(const bf16x8*)&wbase[1 * 16 * 768 + kb * 32 + r * 8];
        bf16x8 b2 = *(const bf16x8*)&wbase[2 * 16 * 768 + kb * 32 + r * 8];
        bf16x8 b3 = *(const bf16x8*)&wbase[3 * 16 * 768 + kb * 32 + r * 8];
        acc0 = __builtin_amdgcn_mfma_f32_16x16x32_bf16(ah, b0, acc0, 0, 0, 0);
        acc0 = __builtin_amdgcn_mfma_f32_16x16x32_bf16(al, b0, acc0, 0, 0, 0);
        acc1 = __builtin_amdgcn_mfma_f32_16x16x32_bf16(ah, b1, acc1, 0, 0, 0);
        acc1 = __builtin_amdgcn_mfma_f32_16x16x32_bf16(al, b1, acc1, 0, 0, 0);
        acc2 = __builtin_amdgcn_mfma_f32_16x16x32_bf16(ah, b2, acc2, 0, 0, 0);
        acc2 = __builtin_amdgcn_mfma_f32_16x16x32_bf16(al, b2, acc2, 0, 0, 0);
        acc3 = __builtin_amdgcn_mfma_f32_16x16x32_bf16(ah, b3, acc3, 0, 0, 0);
        acc3 = __builtin_amdgcn_mfma_f32_16x16x32_bf16(al, b3, acc3, 0, 0, 0);
      }
      // all D rows identical -> lane holds col (lane&15) of each n-tile in reg 0.
      int nt = lane >> 4;
      float gv = (nt == 0) ? acc0[0] : (nt == 1) ? acc1[0] : (nt == 2) ? acc2[0] : acc3[0];
      gates[w * 64 + nt * 16 + q] = gv;
    }
    __syncthreads();
    // ---- LSTM combine (threads 0-255, cell = hc) ----
    if (tid < 256){
      float4 xv = xwd[((size_t)t * 16 + blk) * 256 + tid];
      float s0 = xv.x + gates[tid];
      float s1 = xv.y + gates[256 + tid];
      float s2 = xv.z + gates[512 + tid];
      float s3 = xv.w + gates[768 + tid];
      float cv = sigm(s1) * c_lds[tid] + sigm(s0) * tanh_f(s2);
      float hv = sigm(s3) * tanh_f(cv);
      c_lds[tid] = cv;
      hf[tid] = hv;
      u16 hi = f2bf(hv);
      a_hi[512 + tid] = hi;
      a_lo[512 + tid] = f2bf(hv - bf2f(hi));
      Abf[((size_t)t * 16 + blk) * 768 + 512 + tid] = hi;
    }
    __syncthreads();
    // ---- P2: hws = Wsb + h @ Ws ----
    {
      int j2 = tid & 255, kq = tid >> 8;
      float a2 = 0.f;
      for (int k = kq * 64; k < kq * 64 + 64; ++k) a2 += hf[k] * Ws[k * 256 + j2];
      scratch[kq * 256 + j2] = a2;
    }
    __syncthreads();
    if (tid < 256) hws[tid] = Wsb[tid] + scratch[tid] + scratch[256 + tid] + scratch[512 + tid] + scratch[768 + tid];
    __syncthreads();
    // ---- P3: scores ----
    {
      float4 hw4 = *(const float4*)&hws[4 * lane];
      for (int s = w; s < 400; s += 16){
        float cvv = cov[s];
        const u16* fp = feat + ((size_t)blk * 400 + s) * 256 + 4 * lane;
        u32 p0 = *(const u32*)fp; u32 p1 = *(const u32*)(fp + 2);
        float f0 = bf2f((u16)(p0 & 0xffff)) + hw4.x + cvv * wc4.x;
        float f1 = bf2f((u16)(p0 >> 16))    + hw4.y + cvv * wc4.y;
        float f2 = bf2f((u16)(p1 & 0xffff)) + hw4.z + cvv * wc4.z;
        float f3 = bf2f((u16)(p1 >> 16))    + hw4.w + cvv * wc4.w;
        float scv = tanh_f(f0) * vv4.x + tanh_f(f1) * vv4.y + tanh_f(f2) * vv4.z + tanh_f(f3) * vv4.w;
#pragma unroll
        for (int m = 32; m; m >>= 1) scv += __shfl_xor(scv, m);
        if (lane == 0) sc_s[s] = (src[blk * 400 + s] == 0) ? -1e9f : scv;
      }
    }
    __syncthreads();
    // ---- P4: softmax ----
    {
      float mv = (tid < 400) ? sc_s[tid] : -1e30f;
#pragma unroll
      for (int m = 32; m; m >>= 1) mv = fmaxf(mv, __shfl_xor(mv, m));
      if (lane == 0) red1[w] = mv;
      __syncthreads();
      float mx = red1[0];
#pragma unroll
      for (int i = 1; i < 16; ++i) mx = fmaxf(mx, red1[i]);
      float ev = 0.f;
      if (tid < 400){ ev = __expf(sc_s[tid] - mx); at_s[tid] = ev; }
#pragma unroll
      for (int m = 32; m; m >>= 1) ev += __shfl_xor(ev, m);
      if (lane == 0) red2[w] = ev;
      __syncthreads();
      float sum = 0.f;
#pragma unroll
      for (int i = 0; i < 16; ++i) sum += red2[i];
      float inv = 1.f / sum;
      if (tid < 400) at_s[tid] *= inv;
    }
    __syncthreads();
    // ---- P5: context ----
    {
      int c2 = (tid & 255) * 2, sh = tid >> 8;
      float a0 = 0.f, a1 = 0.f;
      const u16* eb = enc_out + (size_t)blk * 400 * 512 + c2;
      for (int s = sh * 100; s < sh * 100 + 100; ++s){
        u32 p = *(const u32*)&eb[(size_t)s * 512];
        float av = at_s[s];
        a0 += av * bf2f((u16)(p & 0xffff));
        a1 += av * bf2f((u16)(p >> 16));
      }
      scratch[sh * 1024 + c2] = a0;
      scratch[sh * 1024 + c2 + 1] = a1;
    }
    __syncthreads();
    if (tid < 512){
      float cval = scratch[tid] + scratch[1024 + tid] + scratch[2048 + tid] + scratch[3072 + tid];
      ctx_s[tid] = cval;
      u16 hi = f2bf(cval);
      a_hi[tid] = hi;
      a_lo[tid] = f2bf(cval - bf2f(hi));
      Abf[((size_t)t * 16 + blk) * 768 + tid] = hi;
    }
    __syncthreads();
    // ---- P6: coverage/pgen ----
    {
      float clp = 0.f, scp = 0.f, pgp = 0.f;
      int tg = tgt_ext[blk * 50 + t];
      if (tid < 400){
        float a = at_s[tid];
        float cvv = cov[tid];
        clp = fminf(a, cvv);
        cov[tid] = cvv + a;
        if (src_ext[blk * 400 + tid] == tg) scp = a;
      }
      if (tid < 512) pgp = ctx_s[tid] * pgW[tid];
      else if (tid < 768) pgp = hf[tid - 512] * pgW[tid];
#pragma unroll
      for (int m = 32; m; m >>= 1){
        clp += __shfl_xor(clp, m);
        scp += __shfl_xor(scp, m);
        pgp += __shfl_xor(pgp, m);
      }
      if (lane == 0){ red1[w] = clp; red2[w] = scp; red3[w] = pgp; }
      __syncthreads();
      if (tid == 0){
        float cl = 0.f, sc2 = 0.f, pgs = 0.f;
#pragma unroll
        for (int i = 0; i < 16; ++i){ cl += red1[i]; sc2 += red2[i]; pgs += red3[i]; }
        float pg = sigm(pgs + pg_emb[t * 16 + blk] + pgb[0] + pgbias[0]);
        pg = fminf(fmaxf(pg, 0.1f), 0.9f);
        pg_all[t * 16 + blk] = pg; cvl_all[t * 16 + blk] = cl; sct_all[t * 16 + blk] = sc2;
      }
    }
    __syncthreads();
  }
}

// ---------------- batched vocab ----------------
__global__ __launch_bounds__(256) void k_vgemm(const u16* __restrict__ Abf, const u16* __restrict__ vWt,
    const float* __restrict__ vb, const int* __restrict__ tgt_ext,
    float* __restrict__ mpart2, float* __restrict__ spart2, float* __restrict__ ltgt_all){
  int nslab = blockIdx.x, mslab = blockIdx.y;
  int tid = threadIdx.x;
  int w = tid >> 6, lane = tid & 63, q = lane & 15, r = lane >> 4;
  int m0 = mslab * 80;
  int n0w = nslab * 256 + w * 64;
  f32x4 acc[5][4];
#pragma unroll
  for (int mt = 0; mt < 5; ++mt)
#pragma unroll
    for (int nt = 0; nt < 4; ++nt){ acc[mt][nt][0]=0.f; acc[mt][nt][1]=0.f; acc[mt][nt][2]=0.f; acc[mt][nt][3]=0.f; }

  for (int kb = 0; kb < 24; ++kb){
    bf16x8 bfrag[4], afrag[5];
#pragma unroll
    for (int nt = 0; nt < 4; ++nt)
      bfrag[nt] = *(const bf16x8*)&vWt[(size_t)(n0w + nt * 16 + q) * 768 + kb * 32 + r * 8];
#pragma unroll
    for (int mt = 0; mt < 5; ++mt)
      afrag[mt] = *(const bf16x8*)&Abf[(size_t)(m0 + mt * 16 + q) * 768 + kb * 32 + r * 8];
#pragma unroll
    for (int mt = 0; mt < 5; ++mt)
#pragma unroll
      for (int nt = 0; nt < 4; ++nt)
        acc[mt][nt] = __builtin_amdgcn_mfma_f32_16x16x32_bf16(afrag[mt], bfrag[nt], acc[mt][nt], 0, 0, 0);
  }
  float vbc[4];
#pragma unroll
  for (int nt = 0; nt < 4; ++nt) vbc[nt] = vb[n0w + nt * 16 + q];

  __shared__ float pm[4][80], ps[4][80];
#pragma unroll
  for (int mt = 0; mt < 5; ++mt){
#pragma unroll
    for (int rg = 0; rg < 4; ++rg){
      int row = m0 + mt * 16 + 4 * r + rg;
      int tg = tgt_ext[(row & 15) * 50 + (row >> 4)];
      float v0 = acc[mt][0][rg] + vbc[0];
      float v1 = acc[mt][1][rg] + vbc[1];
      float v2 = acc[mt][2][rg] + vbc[2];
      float v3 = acc[mt][3][rg] + vbc[3];
      if (n0w + 0 * 16 + q == tg) ltgt_all[row] = v0;
      if (n0w + 1 * 16 + q == tg) ltgt_all[row] = v1;
      if (n0w + 2 * 16 + q == tg) ltgt_all[row] = v2;
      if (n0w + 3 * 16 + q == tg) ltgt_all[row] = v3;
      float mx = fmaxf(fmaxf(v0, v1), fmaxf(v2, v3));
#pragma unroll
      for (int mk = 1; mk < 16; mk <<= 1) mx = fmaxf(mx, __shfl_xor(mx, mk));
      float se = __expf(v0 - mx) + __expf(v1 - mx) + __expf(v2 - mx) + __expf(v3 - mx);
#pragma unroll
      for (int mk = 1; mk < 16; mk <<= 1) se += __shfl_xor(se, mk);
      if (q == 0){ pm[w][mt * 16 + 4 * r + rg] = mx; ps[w][mt * 16 + 4 * r + rg] = se; }
    }
  }
  __syncthreads();
  if (tid < 80){
    float m = pm[0][tid], s = ps[0][tid];
#pragma unroll
    for (int w2 = 1; w2 < 4; ++w2){
      float om = pm[w2][tid], os = ps[w2][tid];
      float M = fmaxf(m, om);
      s = s * __expf(m - M) + os * __expf(om - M);
      m = M;
    }
    mpart2[(size_t)(m0 + tid) * 125 + nslab] = m;
    spart2[(size_t)(m0 + tid) * 125 + nslab] = s;
  }
}

__global__ void k_comb2(const float* __restrict__ mpart2, const float* __restrict__ spart2,
                        const float* __restrict__ ltgt_all, const float* __restrict__ pg_all,
                        const float* __restrict__ cvl_all, const float* __restrict__ sct_all,
                        const int* __restrict__ tgt_ext, const float* __restrict__ lam,
                        float* __restrict__ loss_g, float* __restrict__ valid_g){
  int t = blockIdx.x; int tid = threadIdx.x;
  int b = tid >> 4, l16 = tid & 15;
  int row = t * 16 + b;
  float m = -1e30f, s = 0.f;
  for (int i = l16; i < 125; i += 16){
    float om = mpart2[(size_t)row * 125 + i], os = spart2[(size_t)row * 125 + i];
    float M = fmaxf(m, om);
    s = s * __expf(m - M) + os * __expf(om - M);
    m = M;
  }
#pragma unroll
  for (int mk = 1; mk < 16; mk <<= 1){
    float om = __shfl_xor(m, mk), os = __shfl_xor(s, mk);
    float M = fmaxf(m, om);
    s = s * __expf(m - M) + os * __expf(om - M);
    m = M;
  }
  if (l16 == 0){
    int tg = tgt_ext[b * 50 + t];
    float pv = (tg < 32000) ? (__expf(ltgt_all[row] - m) / s) : 0.f;
    float pg = pg_all[row];
    float pf = pg * pv + (1.f - pg) * sct_all[row];
    float sl = -__logf(pf + 1e-12f);
    float msk = (tg != 0) ? 1.f : 0.f;
    loss_g[row] = (sl + lam[0] * cvl_all[row]) * msk;
    valid_g[row] = msk;
  }
}

__global__ void k_final(const float* __restrict__ loss_g, const float* __restrict__ valid_g, float* __restrict__ out){
  __shared__ float r1[256], r2[256];
  int tid = threadIdx.x;
  float a = 0.f, v = 0.f;
  for (int i = tid; i < 800; i += 256){ a += loss_g[i]; v += valid_g[i]; }
  r1[tid] = a; r2[tid] = v; __syncthreads();
  for (int off = 128; off; off >>= 1){
    if (tid < off){ r1[tid] += r1[tid + off]; r2[tid] += r2[tid + off]; }
    __syncthreads();
  }
  if (tid == 0) out[0] = r1[0] / fmaxf(r2[0], 1.f);
}

extern "C" void kernel_launch(void* const* d_in, const int* in_sizes, int n_in,
                              void* d_out, int out_size, void* d_ws, size_t ws_size,
                              hipStream_t stream){
  const int*   src     = (const int*)  d_in[0];
  const int*   src_ext = (const int*)  d_in[1];
  const int*   dec_in  = (const int*)  d_in[2];
  const int*   tgt_ext = (const int*)  d_in[3];
  const float* enc_emb = (const float*)d_in[5];
  const float* eWihF   = (const float*)d_in[6];
  const float* eWhhF   = (const float*)d_in[7];
  const float* ebF     = (const float*)d_in[8];
  const float* eWihB   = (const float*)d_in[9];
  const float* eWhhB   = (const float*)d_in[10];
  const float* ebB     = (const float*)d_in[11];
  const float* rhW     = (const float*)d_in[12];
  const float* rhb     = (const float*)d_in[13];
  const float* rcW     = (const float*)d_in[14];
  const float* rcb     = (const float*)d_in[15];
  const float* dec_emb = (const float*)d_in[16];
  const float* dWih    = (const float*)d_in[17];
  const float* dWhh    = (const float*)d_in[18];
  const float* db_     = (const float*)d_in[19];
  const float* aWh     = (const float*)d_in[20];
  const float* aWs     = (const float*)d_in[21];
  const float* aWsb    = (const float*)d_in[22];
  const float* aWc     = (const float*)d_in[23];
  const float* av      = (const float*)d_in[24];
  const float* pgW     = (const float*)d_in[25];
  const float* pgb     = (const float*)d_in[26];
  const float* vW      = (const float*)d_in[27];
  const float* vb      = (const float*)d_in[28];
  const float* lam     = (const float*)d_in[29];
  const float* pgbias  = (const float*)d_in[30];
  (void)in_sizes; (void)n_in; (void)out_size; (void)ws_size;

  char* w = (char*)d_ws;
  size_t off = 0;
  auto alloc = [&](size_t bytes) -> char* {
    char* p = w + off; off += (bytes + 255) & ~(size_t)255; return p;
  };
  u16*     xw      = (u16*)    alloc(2ull * 400 * 1024 * 16 * 2);
  u16*     whhp    = (u16*)    alloc(2ull * 1024 * 256 * 2);
  u16*     decwt   = (u16*)    alloc(1024ull * 768 * 2);
  u16*     enc_out = (u16*)    alloc(16ull * 400 * 512 * 2);
  u16*     feat    = (u16*)    alloc(16ull * 400 * 256 * 2);
  float*   hfin    = (float*)  alloc(2 * 16 * 256 * 4);
  float*   cfin    = (float*)  alloc(2 * 16 * 256 * 4);
  float*   h0buf   = (float*)  alloc(16 * 256 * 4);
  float*   c0buf   = (float*)  alloc(16 * 256 * 4);
  float4*  xwd     = (float4*) alloc(50ull * 16 * 256 * 16);
  float*   pg_emb  = (float*)  alloc(800 * 4);
  u32*     hpub    = (u32*)    alloc(8ull * 2048 * 4);
  u32*     flags   = (u32*)    alloc(4 * 32 * 4);
  u16*     Abf     = (u16*)    alloc(800ull * 768 * 2);
  float*   ltgt_all= (float*)  alloc(800 * 4);
  float*   pg_all  = (float*)  alloc(800 * 4);
  float*   cvl_all = (float*)  alloc(800 * 4);
  float*   sct_all = (float*)  alloc(800 * 4);
  float*   loss_g  = (float*)  alloc(800 * 4);
  float*   valid_g = (float*)  alloc(800 * 4);
  float*   mpart2  = (float*)  alloc(800ull * 125 * 4);
  float*   spart2  = (float*)  alloc(800ull * 125 * 4);
  u16*     vWt     = (u16*)    alloc(32000ull * 768 * 2);

  hipMemsetAsync(flags, 0, 4 * 32 * 4, stream);

  hipLaunchKernelGGL(k_pack_whh2,  dim3(2048),  dim3(256), 0, stream, eWhhF, eWhhB, whhp);
  hipLaunchKernelGGL(k_pack_decwt, dim3(1024),  dim3(256), 0, stream, dWih, dWhh, decwt);
  hipLaunchKernelGGL(k_pack_vwt,   dim3(500, 12), dim3(256), 0, stream, vW, vWt);
  hipLaunchKernelGGL(k_enc_pre2,   dim3(800),   dim3(256), 0, stream, src, enc_emb, eWihF, ebF, eWihB, ebB, xw);
  hipLaunchKernelGGL(k_dec_pre,    dim3(800),   dim3(256), 0, stream, dec_in, dec_emb, dWih, db_, pgW, xwd, pg_emb);
  hipLaunchKernelGGL(k_enc_lstm4,  dim3(4),     dim3(512), 0, stream, xw, whhp, enc_out, hfin, cfin, hpub, flags);
  hipLaunchKernelGGL(k_reduce,     dim3(16),    dim3(256), 0, stream, hfin, cfin, rhW, rhb, rcW, rcb, h0buf, c0buf);
  hipLaunchKernelGGL(k_encfeat,    dim3(400),   dim3(256), 0, stream, enc_out, aWh, feat);
  hipLaunchKernelGGL(k_dec_loop3,  dim3(16),    dim3(1024), 0, stream,
                     decwt, xwd, h0buf, c0buf, feat, enc_out, src, src_ext, tgt_ext,
                     aWs, aWsb, aWc, av, pgW, pg_emb, pgb, pgbias,
                     Abf, pg_all, cvl_all, sct_all);
  hipLaunchKernelGGL(k_vgemm,  dim3(125, 10), dim3(256), 0, stream, Abf, vWt, vb, tgt_ext, mpart2, spart2, ltgt_all);
  hipLaunchKernelGGL(k_comb2,  dim3(50), dim3(256), 0, stream, mpart2, spart2, ltgt_all,
                     pg_all, cvl_all, sct_all, tgt_ext, lam, loss_g, valid_g);
  hipLaunchKernelGGL(k_final, dim3(1), dim3(256), 0, stream, loss_g, valid_g, (float*)d_out);
}

// Round 9
// 4669.263 us; speedup vs baseline: 1.7943x; 1.6755x over previous
//
#include <hip/hip_runtime.h>
#include <math.h>

typedef unsigned short u16;
typedef unsigned int   u32;
typedef unsigned long long u64;
typedef __attribute__((ext_vector_type(8))) short bf16x8;
typedef __attribute__((ext_vector_type(4))) float f32x4;

#define DEVI static __device__ __forceinline__

DEVI float bf2f(u16 u){ u32 x = ((u32)u) << 16; float f; __builtin_memcpy(&f, &x, 4); return f; }
DEVI u16 f2bf(float f){ u32 x; __builtin_memcpy(&x, &f, 4); u32 r = (x + 0x7fffu + ((x >> 16) & 1u)) >> 16; return (u16)r; }
DEVI float sigm(float x){ return 1.f / (1.f + __expf(-x)); }
DEVI float tanh_f(float x){ float e = __expf(2.f * x); return 1.f - 2.f / (e + 1.f); }

// ---------------- pack kernels ----------------
__global__ void k_pack_whh2(const float* __restrict__ Wf, const float* __restrict__ Wb, u16* __restrict__ out){
  int blk = blockIdx.x;             // 2*1024
  int d = blk >> 10, n = blk & 1023;
  const float* W = d ? Wb : Wf;
  int k = threadIdx.x;
  out[((size_t)d * 1024 + n) * 256 + k] = f2bf(W[(size_t)k * 1024 + n]);
}

// decoder weights transposed: decwt[n][k], n = gate*256+hc, k<512 -> Wih row 128+k, else Whh row k-512
__global__ void k_pack_decwt(const float* __restrict__ Wih, const float* __restrict__ Whh, u16* __restrict__ out){
  int n = blockIdx.x;               // 1024
  for (int k = threadIdx.x; k < 768; k += 256){
    const float* row = (k < 512) ? (Wih + (size_t)(128 + k) * 1024) : (Whh + (size_t)(k - 512) * 1024);
    out[(size_t)n * 768 + k] = f2bf(row[n]);
  }
}

// attn_Ws f32 -> bf16 (same [k][j] layout)
__global__ void k_pack_ws(const float* __restrict__ Ws, u16* __restrict__ out){
  int i = blockIdx.x * 256 + threadIdx.x;   // 256 blocks
  out[i] = f2bf(Ws[i]);
}

// vW [768][32000] f32 -> vWt [32000][768] bf16
__global__ __launch_bounds__(256) void k_pack_vwt(const float* __restrict__ vW, u16* __restrict__ vWt){
  __shared__ float ts[64][65];
  int nt = blockIdx.x, kt = blockIdx.y;   // 500 x 12
  int tid = threadIdx.x;
#pragma unroll
  for (int i = 0; i < 16; ++i){
    int idx = tid + i * 256;
    int kl = idx >> 6, nl = idx & 63;
    ts[kl][nl] = vW[(size_t)(kt * 64 + kl) * 32000 + nt * 64 + nl];
  }
  __syncthreads();
#pragma unroll
  for (int i = 0; i < 16; ++i){
    int idx = tid + i * 256;
    int nl = idx >> 6, kl = idx & 63;
    vWt[(size_t)(nt * 64 + nl) * 768 + kt * 64 + kl] = f2bf(ts[kl][nl]);
  }
}

// ---------------- encoder ----------------
// xw[d][s][n][b] bf16 of emb@Wih + bias   (n = gate*256 + hc)
__global__ __launch_bounds__(256) void k_enc_pre2(const int* __restrict__ src, const float* __restrict__ emb,
                          const float* __restrict__ Wf, const float* __restrict__ bf_,
                          const float* __restrict__ Wb, const float* __restrict__ bb_,
                          u16* __restrict__ xw){
  int d = blockIdx.x / 400, s = blockIdx.x % 400;
  const float* Wih = d ? Wb : Wf; const float* bias = d ? bb_ : bf_;
  __shared__ float es[16][128];
  int tid = threadIdx.x;
  for (int idx = tid; idx < 16 * 128; idx += 256){
    int b = idx >> 7, e = idx & 127;
    es[b][e] = emb[(size_t)src[b * 400 + s] * 128 + e];
  }
  __syncthreads();
  int j = tid;
  float a[4][16];
#pragma unroll
  for (int g = 0; g < 4; ++g){
    float bv = bias[g * 256 + j];
#pragma unroll
    for (int b = 0; b < 16; ++b) a[g][b] = bv;
  }
  for (int e4 = 0; e4 < 32; ++e4){
    float w0[4], w1[4], w2[4], w3[4];
#pragma unroll
    for (int u = 0; u < 4; ++u){
      int e = e4 * 4 + u;
      w0[u] = Wih[(size_t)e * 1024 + j];
      w1[u] = Wih[(size_t)e * 1024 + 256 + j];
      w2[u] = Wih[(size_t)e * 1024 + 512 + j];
      w3[u] = Wih[(size_t)e * 1024 + 768 + j];
    }
#pragma unroll
    for (int b = 0; b < 16; ++b){
      float4 x = *(const float4*)&es[b][e4 * 4];
      a[0][b] += x.x * w0[0] + x.y * w0[1] + x.z * w0[2] + x.w * w0[3];
      a[1][b] += x.x * w1[0] + x.y * w1[1] + x.z * w1[2] + x.w * w1[3];
      a[2][b] += x.x * w2[0] + x.y * w2[1] + x.z * w2[2] + x.w * w2[3];
      a[3][b] += x.x * w3[0] + x.y * w3[1] + x.z * w3[2] + x.w * w3[3];
    }
  }
#pragma unroll
  for (int g = 0; g < 4; ++g){
    u16 tmp[16];
#pragma unroll
    for (int b = 0; b < 16; ++b) tmp[b] = f2bf(a[g][b]);
    uint4* dst = (uint4*)&xw[(((size_t)(d * 400 + s)) * 1024 + g * 256 + j) * 16];
    dst[0] = *(uint4*)&tmp[0];
    dst[1] = *(uint4*)&tmp[8];
  }
}

// Encoder LSTM: 4 blocks (2 dir x 2 hc-halves), 512 thr (8 waves). (unchanged, proven)
__global__ __launch_bounds__(512, 2) void k_enc_lstm4(
    const u16* __restrict__ xw, const u16* __restrict__ wpk,
    u16* __restrict__ enc_out, float* __restrict__ hfin, float* __restrict__ cfin,
    u32* __restrict__ hpub, u32* __restrict__ flags)
{
  const int blk = blockIdx.x;
  const int d = blk >> 1, bp = blk & 1;
  const int tid = threadIdx.x;
  const int w = tid >> 6, lane = tid & 63;
  const int q = lane & 15, r = lane >> 4;
  const int g = w >> 1, sub = w & 1;

  __shared__ u16 hhi[16][264];
  __shared__ u16 hlo[16][264];
  __shared__ float gex[4][16][132];

  for (int idx = tid; idx < 16 * 264; idx += 512){
    hhi[idx / 264][idx % 264] = 0;
    hlo[idx / 264][idx % 264] = 0;
  }

  const u16* wb = wpk + (size_t)d * 1024 * 256;
  int nn[4];
  bf16x8 wreg[4][8];
#pragma unroll
  for (int nt = 0; nt < 4; ++nt){
    nn[nt] = g * 256 + bp * 128 + sub * 64 + nt * 16 + q;
#pragma unroll
    for (int kb = 0; kb < 8; ++kb)
      wreg[nt][kb] = *(const bf16x8*)&wb[(size_t)nn[nt] * 256 + kb * 32 + r * 8];
  }

  const int cb = tid >> 5;
  const int i4 = (tid & 31) * 4;
  float c[4] = {0.f, 0.f, 0.f, 0.f}, hl[4] = {0.f, 0.f, 0.f, 0.f};

  u32* myflag = flags + (d * 2 + bp) * 32;
  u32* rmflag = flags + (d * 2 + (bp ^ 1)) * 32;

  int s0 = d ? 399 : 0;
  ushort4 xv[4];
#pragma unroll
  for (int nt = 0; nt < 4; ++nt)
    xv[nt] = *(const ushort4*)&xw[(((size_t)(d * 400 + s0)) * 1024 + nn[nt]) * 16 + 4 * r];
  __syncthreads();

  for (int it = 0; it < 400; ++it){
    int s = d ? (399 - it) : it;
    f32x4 acc[4];
#pragma unroll
    for (int nt = 0; nt < 4; ++nt){
      acc[nt][0] = bf2f(xv[nt].x); acc[nt][1] = bf2f(xv[nt].y);
      acc[nt][2] = bf2f(xv[nt].z); acc[nt][3] = bf2f(xv[nt].w);
    }
#pragma unroll
    for (int kb = 0; kb < 8; ++kb){
      bf16x8 ah = *(const bf16x8*)&hhi[q][kb * 32 + r * 8];
      bf16x8 al = *(const bf16x8*)&hlo[q][kb * 32 + r * 8];
#pragma unroll
      for (int nt = 0; nt < 4; ++nt){
        acc[nt] = __builtin_amdgcn_mfma_f32_16x16x32_bf16(ah, wreg[nt][kb], acc[nt], 0, 0, 0);
        acc[nt] = __builtin_amdgcn_mfma_f32_16x16x32_bf16(al, wreg[nt][kb], acc[nt], 0, 0, 0);
      }
    }
#pragma unroll
    for (int nt = 0; nt < 4; ++nt)
#pragma unroll
      for (int rg = 0; rg < 4; ++rg)
        gex[g][4 * r + rg][sub * 64 + nt * 16 + q] = acc[nt][rg];
    __syncthreads();

    u32 pk[4];
#pragma unroll
    for (int j = 0; j < 4; ++j){
      int hcl = i4 + j;
      float gi = gex[0][cb][hcl], gf = gex[1][cb][hcl];
      float gg = gex[2][cb][hcl], go = gex[3][cb][hcl];
      float cv = sigm(gf) * c[j] + sigm(gi) * tanh_f(gg);
      float hv = sigm(go) * tanh_f(cv);
      c[j] = cv; hl[j] = hv;
      u16 hi = f2bf(hv);
      u16 lo = f2bf(hv - bf2f(hi));
      pk[j] = ((u32)hi << 16) | lo;
    }
    {
      u64 hi64 = (u64)(pk[0] >> 16) | ((u64)(pk[1] >> 16) << 16)
               | ((u64)(pk[2] >> 16) << 32) | ((u64)(pk[3] >> 16) << 48);
      u64 lo64 = (u64)(pk[0] & 0xffffu) | ((u64)(pk[1] & 0xffffu) << 16)
               | ((u64)(pk[2] & 0xffffu) << 32) | ((u64)(pk[3] & 0xffffu) << 48);
      *(u64*)&hhi[cb][bp * 128 + i4] = hi64;
      *(u64*)&hlo[cb][bp * 128 + i4] = lo64;
      *(u64*)&enc_out[((size_t)cb * 400 + s) * 512 + d * 256 + bp * 128 + i4] = hi64;
    }
    if (it < 399){
      int par = (it + 1) & 1;
      u32* hp_w = hpub + (((size_t)par * 2 + d) * 2 + bp) * 2048;
#pragma unroll
      for (int j = 0; j < 4; ++j)
        __hip_atomic_store(&hp_w[cb * 128 + i4 + j], pk[j], __ATOMIC_RELAXED, __HIP_MEMORY_SCOPE_AGENT);
      int sn = d ? (399 - (it + 1)) : (it + 1);
#pragma unroll
      for (int nt = 0; nt < 4; ++nt)
        xv[nt] = *(const ushort4*)&xw[(((size_t)(d * 400 + sn)) * 1024 + nn[nt]) * 16 + 4 * r];
      __syncthreads();
      if (tid == 0){
        __hip_atomic_store(myflag, (u32)(it + 1), __ATOMIC_RELEASE, __HIP_MEMORY_SCOPE_AGENT);
        while (__hip_atomic_load(rmflag, __ATOMIC_ACQUIRE, __HIP_MEMORY_SCOPE_AGENT) < (u32)(it + 1))
          __builtin_amdgcn_s_sleep(1);
      }
      __syncthreads();
      const u32* hp_r = hpub + (((size_t)par * 2 + d) * 2 + (bp ^ 1)) * 2048;
      u32 rp[4];
#pragma unroll
      for (int j = 0; j < 4; ++j)
        rp[j] = __hip_atomic_load(&hp_r[cb * 128 + i4 + j], __ATOMIC_RELAXED, __HIP_MEMORY_SCOPE_AGENT);
      u64 hi64 = (u64)(rp[0] >> 16) | ((u64)(rp[1] >> 16) << 16)
               | ((u64)(rp[2] >> 16) << 32) | ((u64)(rp[3] >> 16) << 48);
      u64 lo64 = (u64)(rp[0] & 0xffffu) | ((u64)(rp[1] & 0xffffu) << 16)
               | ((u64)(rp[2] & 0xffffu) << 32) | ((u64)(rp[3] & 0xffffu) << 48);
      *(u64*)&hhi[cb][(bp ^ 1) * 128 + i4] = hi64;
      *(u64*)&hlo[cb][(bp ^ 1) * 128 + i4] = lo64;
      __syncthreads();
    }
  }
#pragma unroll
  for (int j = 0; j < 4; ++j){
    hfin[(d * 16 + cb) * 256 + bp * 128 + i4 + j] = hl[j];
    cfin[(d * 16 + cb) * 256 + bp * 128 + i4 + j] = c[j];
  }
}

__global__ void k_reduce(const float* __restrict__ hfin, const float* __restrict__ cfin,
                         const float* __restrict__ rhW, const float* __restrict__ rhb,
                         const float* __restrict__ rcW, const float* __restrict__ rcb,
                         float* __restrict__ h0buf, float* __restrict__ c0buf){
  int b = blockIdx.x, j = threadIdx.x;
  float ah = rhb[j], ac = rcb[j];
  for (int k = 0; k < 256; ++k){
    float hv = hfin[b * 256 + k], cv = cfin[b * 256 + k];
    ah += hv * rhW[k * 256 + j];
    ac += cv * rcW[k * 256 + j];
  }
  for (int k = 0; k < 256; ++k){
    float hv = hfin[(16 + b) * 256 + k], cv = cfin[(16 + b) * 256 + k];
    ah += hv * rhW[(256 + k) * 256 + j];
    ac += cv * rcW[(256 + k) * 256 + j];
  }
  h0buf[b * 256 + j] = tanh_f(ah);
  c0buf[b * 256 + j] = tanh_f(ac);
}

__global__ void k_encfeat(const u16* __restrict__ enc_out, const float* __restrict__ Wh, u16* __restrict__ feat){
  int blk = blockIdx.x; int b = blk / 25; int sc = blk % 25;
  int j = threadIdx.x;
  float acc[16];
#pragma unroll
  for (int i = 0; i < 16; ++i) acc[i] = 0.f;
  const u32* ebase = (const u32*)(enc_out + ((size_t)b * 400 + sc * 16) * 512);
  for (int k2 = 0; k2 < 256; ++k2){
    float wa = Wh[(2 * k2) * 256 + j], wb_ = Wh[(2 * k2 + 1) * 256 + j];
#pragma unroll
    for (int ss = 0; ss < 16; ++ss){
      u32 p = ebase[ss * 256 + k2];
      acc[ss] += bf2f((u16)(p & 0xffff)) * wa + bf2f((u16)(p >> 16)) * wb_;
    }
  }
#pragma unroll
  for (int ss = 0; ss < 16; ++ss)
    feat[((size_t)b * 400 + sc * 16 + ss) * 256 + j] = f2bf(acc[ss]);
}

// ---------------- decoder precompute ----------------
__global__ void k_dec_pre(const int* __restrict__ din, const float* __restrict__ emb,
                          const float* __restrict__ Wih, const float* __restrict__ db,
                          const float* __restrict__ pgW,
                          float4* __restrict__ xwd, float* __restrict__ pg_emb){
  int blk = blockIdx.x; int t = blk / 16, b = blk % 16;
  int j = threadIdx.x;
  int id = din[b * 50 + t];
  const float* er = emb + (size_t)id * 128;
  float a0 = db[j], a1 = db[256 + j], a2 = db[512 + j], a3 = db[768 + j];
  for (int e = 0; e < 128; ++e){
    float x = er[e];
    const float* wr = Wih + (size_t)e * 1024;
    a0 += x * wr[j]; a1 += x * wr[256 + j]; a2 += x * wr[512 + j]; a3 += x * wr[768 + j];
  }
  xwd[(size_t)blk * 256 + j] = make_float4(a0, a1, a2, a3);
  __shared__ float red[256];
  float pe = 0.f;
  if (j < 128) pe = er[j] * pgW[768 + j];
  red[j] = pe; __syncthreads();
  for (int off = 128; off; off >>= 1){ if (j < off) red[j] += red[j + off]; __syncthreads(); }
  if (j == 0) pg_emb[blk] = red[0];
}

// ---------------- persistent decoder loop v4 ----------------
// 16 blocks x 512 thr (8 waves). Block g: cell for hc-slice [16g,16g+16) x 4 gates x ALL
// batches, weights REGISTER-RESIDENT (48 VGPR/lane); attention for batch g only.
// Per step: pubH -> flagA -> gatherH -> attn -> pubCtx -> flagB -> P6 -> gatherCtx.
__global__ __launch_bounds__(512, 1) void k_dec_loop4(
    const u16* __restrict__ decwt, const float4* __restrict__ xwd,
    const float* __restrict__ h0buf, const float* __restrict__ c0buf,
    const u16* __restrict__ feat, const u16* __restrict__ enc_out,
    const int* __restrict__ src, const int* __restrict__ src_ext, const int* __restrict__ tgt_ext,
    const u16* __restrict__ Wsbf, const float* __restrict__ Wsb,
    const float* __restrict__ Wc, const float* __restrict__ av_,
    const float* __restrict__ pgW, const float* __restrict__ pg_emb,
    const float* __restrict__ pgb, const float* __restrict__ pgbias,
    u16* __restrict__ Abf, float* __restrict__ pg_all,
    float* __restrict__ cvl_all, float* __restrict__ sct_all,
    u32* __restrict__ dhpub, u32* __restrict__ cxch, u32* __restrict__ dflags)
{
  const int blk = blockIdx.x;
  const int tid = threadIdx.x;
  const int w = tid >> 6, lane = tid & 63;
  const int q = lane & 15, r = lane >> 4;
  const int gate = w & 3, kh = w >> 2;     // wave role for cell MFMA

  __shared__ u16 a_hi[16][792];     // [ctx(512); h(256)] hi bf16, all batches
  __shared__ u16 a_lo[16][792];
  __shared__ float c_lds[16][16];   // own hc-slice, all batches
  __shared__ float scrp[2048];      // cell partials [kh][gate][hcl][batch]
  __shared__ float scratch[2048];   // P2/P5 partials
  __shared__ float ctx_s[512];
  __shared__ float hf[256];
  __shared__ float hws[256];
  __shared__ float cov[400];
  __shared__ float sc_s[400];
  __shared__ float at_s[400];
  __shared__ float red1[8], red2[8], red3[8];

  // register-resident weight slice: n = gate*256 + blk*16 + q, k-half kh
  bf16x8 wreg[12];
#pragma unroll
  for (int i = 0; i < 12; ++i)
    wreg[i] = *(const bf16x8*)&decwt[(size_t)(gate * 256 + blk * 16 + q) * 768 + (kh * 12 + i) * 32 + r * 8];

  // init
  for (int i = tid; i < 16 * 256; i += 512){
    int b = i >> 8, hc = i & 255;
    float hv = h0buf[i];
    u16 hi = f2bf(hv);
    a_hi[b][512 + hc] = hi;
    a_lo[b][512 + hc] = f2bf(hv - bf2f(hi));
    if (b == blk) hf[hc] = hv;
  }
  for (int i = tid; i < 16 * 512; i += 512){
    int b = i >> 9, j = i & 511;
    a_hi[b][j] = 0; a_lo[b][j] = 0;
  }
  if (tid < 256) c_lds[tid >> 4][tid & 15] = c0buf[(tid >> 4) * 256 + blk * 16 + (tid & 15)];
  for (int i = tid; i < 400; i += 512) cov[i] = 0.f;
  float4 wc4 = *(const float4*)&Wc[4 * lane];
  float4 vv4 = *(const float4*)&av_[4 * lane];
  __syncthreads();

  for (int t = 0; t < 50; ++t){
    // ---- cell MFMA: all 16 batches, own 64 n-cols, weights in regs ----
    {
      f32x4 acc = {0.f, 0.f, 0.f, 0.f};
#pragma unroll
      for (int i = 0; i < 12; ++i){
        int kb = kh * 12 + i;
        bf16x8 ah = *(const bf16x8*)&a_hi[q][kb * 32 + r * 8];
        bf16x8 al = *(const bf16x8*)&a_lo[q][kb * 32 + r * 8];
        acc = __builtin_amdgcn_mfma_f32_16x16x32_bf16(ah, wreg[i], acc, 0, 0, 0);
        acc = __builtin_amdgcn_mfma_f32_16x16x32_bf16(al, wreg[i], acc, 0, 0, 0);
      }
#pragma unroll
      for (int rg = 0; rg < 4; ++rg)
        scrp[((kh * 4 + gate) * 16 + q) * 16 + 4 * r + rg] = acc[rg];
    }
    __syncthreads();
    // ---- combine (tid<256: b = tid>>4, hcl = tid&15) + publish h-slice ----
    if (tid < 256){
      int b = tid >> 4, hcl = tid & 15;
      float gi = scrp[((0 + 0) * 16 + hcl) * 16 + b] + scrp[((4 + 0) * 16 + hcl) * 16 + b];
      float gf = scrp[((0 + 1) * 16 + hcl) * 16 + b] + scrp[((4 + 1) * 16 + hcl) * 16 + b];
      float gg = scrp[((0 + 2) * 16 + hcl) * 16 + b] + scrp[((4 + 2) * 16 + hcl) * 16 + b];
      float go = scrp[((0 + 3) * 16 + hcl) * 16 + b] + scrp[((4 + 3) * 16 + hcl) * 16 + b];
      float4 xv = xwd[((size_t)t * 16 + b) * 256 + blk * 16 + hcl];
      float s0 = xv.x + gi, s1 = xv.y + gf, s2 = xv.z + gg, s3 = xv.w + go;
      float cv = sigm(s1) * c_lds[b][hcl] + sigm(s0) * tanh_f(s2);
      float hv = sigm(s3) * tanh_f(cv);
      c_lds[b][hcl] = cv;
      u16 hi = f2bf(hv);
      u16 lo = f2bf(hv - bf2f(hi));
      __hip_atomic_store(&dhpub[blk * 256 + tid], ((u32)hi << 16) | lo, __ATOMIC_RELAXED, __HIP_MEMORY_SCOPE_AGENT);
    }
    __syncthreads();   // drains dhpub stores
    if (tid == 0)
      __hip_atomic_store(&dflags[blk * 32], (u32)(2 * t + 1), __ATOMIC_RELEASE, __HIP_MEMORY_SCOPE_AGENT);
    if (tid < 16){
      while (__hip_atomic_load(&dflags[tid * 32], __ATOMIC_ACQUIRE, __HIP_MEMORY_SCOPE_AGENT) < (u32)(2 * t + 1))
        __builtin_amdgcn_s_sleep(1);
    }
    __syncthreads();
    // ---- gather h: all batches into a_hi/a_lo; own batch into hf + Abf ----
    for (int i = tid; i < 4096; i += 512){
      int g2 = i >> 8, b = (i >> 4) & 15, hcl = i & 15;
      u32 p = __hip_atomic_load(&dhpub[i], __ATOMIC_RELAXED, __HIP_MEMORY_SCOPE_AGENT);
      int hc = g2 * 16 + hcl;
      a_hi[b][512 + hc] = (u16)(p >> 16);
      a_lo[b][512 + hc] = (u16)(p & 0xffffu);
    }
    if (tid < 256){
      u32 p = __hip_atomic_load(&dhpub[(tid >> 4) * 256 + blk * 16 + (tid & 15)], __ATOMIC_RELAXED, __HIP_MEMORY_SCOPE_AGENT);
      u16 hi = (u16)(p >> 16);
      hf[tid] = bf2f(hi) + bf2f((u16)(p & 0xffffu));
      Abf[((size_t)t * 16 + blk) * 768 + 512 + tid] = hi;
    }
    __syncthreads();
    // ---- P2: hws = Wsb + h @ Ws (bf16 weights) ----
    {
      int j2 = tid & 255, kq = tid >> 8;
      float a2 = 0.f;
      for (int k = kq * 128; k < kq * 128 + 128; ++k) a2 += hf[k] * bf2f(Wsbf[k * 256 + j2]);
      scratch[kq * 256 + j2] = a2;
    }
    __syncthreads();
    if (tid < 256) hws[tid] = Wsb[tid] + scratch[tid] + scratch[256 + tid];
    __syncthreads();
    // ---- P3: scores ----
    {
      float4 hw4 = *(const float4*)&hws[4 * lane];
      for (int s = w; s < 400; s += 8){
        float cvv = cov[s];
        const u16* fp = feat + ((size_t)blk * 400 + s) * 256 + 4 * lane;
        u32 p0 = *(const u32*)fp; u32 p1 = *(const u32*)(fp + 2);
        float f0 = bf2f((u16)(p0 & 0xffff)) + hw4.x + cvv * wc4.x;
        float f1 = bf2f((u16)(p0 >> 16))    + hw4.y + cvv * wc4.y;
        float f2 = bf2f((u16)(p1 & 0xffff)) + hw4.z + cvv * wc4.z;
        float f3 = bf2f((u16)(p1 >> 16))    + hw4.w + cvv * wc4.w;
        float scv = tanh_f(f0) * vv4.x + tanh_f(f1) * vv4.y + tanh_f(f2) * vv4.z + tanh_f(f3) * vv4.w;
#pragma unroll
        for (int m = 32; m; m >>= 1) scv += __shfl_xor(scv, m);
        if (lane == 0) sc_s[s] = (src[blk * 400 + s] == 0) ? -1e9f : scv;
      }
    }
    __syncthreads();
    // ---- P4: softmax over 400 ----
    {
      float mv = (tid < 400) ? sc_s[tid] : -1e30f;
#pragma unroll
      for (int m = 32; m; m >>= 1) mv = fmaxf(mv, __shfl_xor(mv, m));
      if (lane == 0) red1[w] = mv;
      __syncthreads();
      float mx = red1[0];
#pragma unroll
      for (int i = 1; i < 8; ++i) mx = fmaxf(mx, red1[i]);
      float ev = 0.f;
      if (tid < 400){ ev = __expf(sc_s[tid] - mx); at_s[tid] = ev; }
#pragma unroll
      for (int m = 32; m; m >>= 1) ev += __shfl_xor(ev, m);
      if (lane == 0) red2[w] = ev;
      __syncthreads();
      float sum = 0.f;
#pragma unroll
      for (int i = 0; i < 8; ++i) sum += red2[i];
      float inv = 1.f / sum;
      if (tid < 400) at_s[tid] *= inv;
    }
    __syncthreads();
    // ---- P5: context ----
    {
      int c2 = (tid & 255) * 2, sh = tid >> 8;
      float a0 = 0.f, a1 = 0.f;
      const u16* eb = enc_out + (size_t)blk * 400 * 512 + c2;
      for (int s = sh * 200; s < sh * 200 + 200; ++s){
        u32 p = *(const u32*)&eb[(size_t)s * 512];
        float av = at_s[s];
        a0 += av * bf2f((u16)(p & 0xffff));
        a1 += av * bf2f((u16)(p >> 16));
      }
      scratch[sh * 1024 + c2] = a0;
      scratch[sh * 1024 + c2 + 1] = a1;
    }
    __syncthreads();
    {
      float cval = scratch[tid] + scratch[1024 + tid];
      ctx_s[tid] = cval;
      Abf[((size_t)t * 16 + blk) * 768 + tid] = f2bf(cval);
      if (t < 49){
        u32 bits; __builtin_memcpy(&bits, &cval, 4);
        __hip_atomic_store(&cxch[blk * 512 + tid], bits, __ATOMIC_RELAXED, __HIP_MEMORY_SCOPE_AGENT);
      }
    }
    __syncthreads();   // drains cxch stores
    if (t < 49 && tid == 0)
      __hip_atomic_store(&dflags[blk * 32], (u32)(2 * t + 2), __ATOMIC_RELEASE, __HIP_MEMORY_SCOPE_AGENT);
    // ---- P6: coverage/pgen (overlaps other blocks) ----
    {
      float clp = 0.f, scp = 0.f, pgp = ctx_s[tid] * pgW[tid];
      int tg = tgt_ext[blk * 50 + t];
      if (tid < 400){
        float a = at_s[tid];
        float cvv = cov[tid];
        clp = fminf(a, cvv);
        cov[tid] = cvv + a;
        if (src_ext[blk * 400 + tid] == tg) scp = a;
      }
      if (tid < 256) pgp += hf[tid] * pgW[512 + tid];
#pragma unroll
      for (int m = 32; m; m >>= 1){
        clp += __shfl_xor(clp, m);
        scp += __shfl_xor(scp, m);
        pgp += __shfl_xor(pgp, m);
      }
      if (lane == 0){ red1[w] = clp; red2[w] = scp; red3[w] = pgp; }
      __syncthreads();
      if (tid == 0){
        float cl = 0.f, sc2 = 0.f, pgs = 0.f;
#pragma unroll
        for (int i = 0; i < 8; ++i){ cl += red1[i]; sc2 += red2[i]; pgs += red3[i]; }
        float pg = sigm(pgs + pg_emb[t * 16 + blk] + pgb[0] + pgbias[0]);
        pg = fminf(fmaxf(pg, 0.1f), 0.9f);
        pg_all[t * 16 + blk] = pg; cvl_all[t * 16 + blk] = cl; sct_all[t * 16 + blk] = sc2;
      }
    }
    __syncthreads();
    // ---- gather ctx from all blocks ----
    if (t < 49){
      if (tid < 16){
        while (__hip_atomic_load(&dflags[tid * 32], __ATOMIC_ACQUIRE, __HIP_MEMORY_SCOPE_AGENT) < (u32)(2 * t + 2))
          __builtin_amdgcn_s_sleep(1);
      }
      __syncthreads();
      for (int i = tid; i < 8192; i += 512){
        int b = i >> 9, j = i & 511;
        u32 bits = __hip_atomic_load(&cxch[i], __ATOMIC_RELAXED, __HIP_MEMORY_SCOPE_AGENT);
        float cval; __builtin_memcpy(&cval, &bits, 4);
        u16 hi = f2bf(cval);
        a_hi[b][j] = hi;
        a_lo[b][j] = f2bf(cval - bf2f(hi));
      }
      __syncthreads();
    }
  }
}

// ---------------- batched vocab ----------------
__global__ __launch_bounds__(256) void k_vgemm(const u16* __restrict__ Abf, const u16* __restrict__ vWt,
    const float* __restrict__ vb, const int* __restrict__ tgt_ext,
    float* __restrict__ mpart2, float* __restrict__ spart2, float* __restrict__ ltgt_all){
  int nslab = blockIdx.x, mslab = blockIdx.y;
  int tid = threadIdx.x;
  int w = tid >> 6, lane = tid & 63, q = lane & 15, r = lane >> 4;
  int m0 = mslab * 80;
  int n0w = nslab * 256 + w * 64;
  f32x4 acc[5][4];
#pragma unroll
  for (int mt = 0; mt < 5; ++mt)
#pragma unroll
    for (int nt = 0; nt < 4; ++nt){ acc[mt][nt][0]=0.f; acc[mt][nt][1]=0.f; acc[mt][nt][2]=0.f; acc[mt][nt][3]=0.f; }

  for (int kb = 0; kb < 24; ++kb){
    bf16x8 bfrag[4], afrag[5];
#pragma unroll
    for (int nt = 0; nt < 4; ++nt)
      bfrag[nt] = *(const bf16x8*)&vWt[(size_t)(n0w + nt * 16 + q) * 768 + kb * 32 + r * 8];
#pragma unroll
    for (int mt = 0; mt < 5; ++mt)
      afrag[mt] = *(const bf16x8*)&Abf[(size_t)(m0 + mt * 16 + q) * 768 + kb * 32 + r * 8];
#pragma unroll
    for (int mt = 0; mt < 5; ++mt)
#pragma unroll
      for (int nt = 0; nt < 4; ++nt)
        acc[mt][nt] = __builtin_amdgcn_mfma_f32_16x16x32_bf16(afrag[mt], bfrag[nt], acc[mt][nt], 0, 0, 0);
  }
  float vbc[4];
#pragma unroll
  for (int nt = 0; nt < 4; ++nt) vbc[nt] = vb[n0w + nt * 16 + q];

  __shared__ float pm[4][80], ps[4][80];
#pragma unroll
  for (int mt = 0; mt < 5; ++mt){
#pragma unroll
    for (int rg = 0; rg < 4; ++rg){
      int row = m0 + mt * 16 + 4 * r + rg;
      int tg = tgt_ext[(row & 15) * 50 + (row >> 4)];
      float v0 = acc[mt][0][rg] + vbc[0];
      float v1 = acc[mt][1][rg] + vbc[1];
      float v2 = acc[mt][2][rg] + vbc[2];
      float v3 = acc[mt][3][rg] + vbc[3];
      if (n0w + 0 * 16 + q == tg) ltgt_all[row] = v0;
      if (n0w + 1 * 16 + q == tg) ltgt_all[row] = v1;
      if (n0w + 2 * 16 + q == tg) ltgt_all[row] = v2;
      if (n0w + 3 * 16 + q == tg) ltgt_all[row] = v3;
      float mx = fmaxf(fmaxf(v0, v1), fmaxf(v2, v3));
#pragma unroll
      for (int mk = 1; mk < 16; mk <<= 1) mx = fmaxf(mx, __shfl_xor(mx, mk));
      float se = __expf(v0 - mx) + __expf(v1 - mx) + __expf(v2 - mx) + __expf(v3 - mx);
#pragma unroll
      for (int mk = 1; mk < 16; mk <<= 1) se += __shfl_xor(se, mk);
      if (q == 0){ pm[w][mt * 16 + 4 * r + rg] = mx; ps[w][mt * 16 + 4 * r + rg] = se; }
    }
  }
  __syncthreads();
  if (tid < 80){
    float m = pm[0][tid], s = ps[0][tid];
#pragma unroll
    for (int w2 = 1; w2 < 4; ++w2){
      float om = pm[w2][tid], os = ps[w2][tid];
      float M = fmaxf(m, om);
      s = s * __expf(m - M) + os * __expf(om - M);
      m = M;
    }
    mpart2[(size_t)(m0 + tid) * 125 + nslab] = m;
    spart2[(size_t)(m0 + tid) * 125 + nslab] = s;
  }
}

__global__ void k_comb2(const float* __restrict__ mpart2, const float* __restrict__ spart2,
                        const float* __restrict__ ltgt_all, const float* __restrict__ pg_all,
                        const float* __restrict__ cvl_all, const float* __restrict__ sct_all,
                        const int* __restrict__ tgt_ext, const float* __restrict__ lam,
                        float* __restrict__ loss_g, float* __restrict__ valid_g){
  int t = blockIdx.x; int tid = threadIdx.x;
  int b = tid >> 4, l16 = tid & 15;
  int row = t * 16 + b;
  float m = -1e30f, s = 0.f;
  for (int i = l16; i < 125; i += 16){
    float om = mpart2[(size_t)row * 125 + i], os = spart2[(size_t)row * 125 + i];
    float M = fmaxf(m, om);
    s = s * __expf(m - M) + os * __expf(om - M);
    m = M;
  }
#pragma unroll
  for (int mk = 1; mk < 16; mk <<= 1){
    float om = __shfl_xor(m, mk), os = __shfl_xor(s, mk);
    float M = fmaxf(m, om);
    s = s * __expf(m - M) + os * __expf(om - M);
    m = M;
  }
  if (l16 == 0){
    int tg = tgt_ext[b * 50 + t];
    float pv = (tg < 32000) ? (__expf(ltgt_all[row] - m) / s) : 0.f;
    float pg = pg_all[row];
    float pf = pg * pv + (1.f - pg) * sct_all[row];
    float sl = -__logf(pf + 1e-12f);
    float msk = (tg != 0) ? 1.f : 0.f;
    loss_g[row] = (sl + lam[0] * cvl_all[row]) * msk;
    valid_g[row] = msk;
  }
}

__global__ void k_final(const float* __restrict__ loss_g, const float* __restrict__ valid_g, float* __restrict__ out){
  __shared__ float r1[256], r2[256];
  int tid = threadIdx.x;
  float a = 0.f, v = 0.f;
  for (int i = tid; i < 800; i += 256){ a += loss_g[i]; v += valid_g[i]; }
  r1[tid] = a; r2[tid] = v; __syncthreads();
  for (int off = 128; off; off >>= 1){
    if (tid < off){ r1[tid] += r1[tid + off]; r2[tid] += r2[tid + off]; }
    __syncthreads();
  }
  if (tid == 0) out[0] = r1[0] / fmaxf(r2[0], 1.f);
}

extern "C" void kernel_launch(void* const* d_in, const int* in_sizes, int n_in,
                              void* d_out, int out_size, void* d_ws, size_t ws_size,
                              hipStream_t stream){
  const int*   src     = (const int*)  d_in[0];
  const int*   src_ext = (const int*)  d_in[1];
  const int*   dec_in  = (const int*)  d_in[2];
  const int*   tgt_ext = (const int*)  d_in[3];
  const float* enc_emb = (const float*)d_in[5];
  const float* eWihF   = (const float*)d_in[6];
  const float* eWhhF   = (const float*)d_in[7];
  const float* ebF     = (const float*)d_in[8];
  const float* eWihB   = (const float*)d_in[9];
  const float* eWhhB   = (const float*)d_in[10];
  const float* ebB     = (const float*)d_in[11];
  const float* rhW     = (const float*)d_in[12];
  const float* rhb     = (const float*)d_in[13];
  const float* rcW     = (const float*)d_in[14];
  const float* rcb     = (const float*)d_in[15];
  const float* dec_emb = (const float*)d_in[16];
  const float* dWih    = (const float*)d_in[17];
  const float* dWhh    = (const float*)d_in[18];
  const float* db_     = (const float*)d_in[19];
  const float* aWh     = (const float*)d_in[20];
  const float* aWs     = (const float*)d_in[21];
  const float* aWsb    = (const float*)d_in[22];
  const float* aWc     = (const float*)d_in[23];
  const float* av      = (const float*)d_in[24];
  const float* pgW     = (const float*)d_in[25];
  const float* pgb     = (const float*)d_in[26];
  const float* vW      = (const float*)d_in[27];
  const float* vb      = (const float*)d_in[28];
  const float* lam     = (const float*)d_in[29];
  const float* pgbias  = (const float*)d_in[30];
  (void)in_sizes; (void)n_in; (void)out_size; (void)ws_size;

  char* w = (char*)d_ws;
  size_t off = 0;
  auto alloc = [&](size_t bytes) -> char* {
    char* p = w + off; off += (bytes + 255) & ~(size_t)255; return p;
  };
  u16*     xw      = (u16*)    alloc(2ull * 400 * 1024 * 16 * 2);
  u16*     whhp    = (u16*)    alloc(2ull * 1024 * 256 * 2);
  u16*     decwt   = (u16*)    alloc(1024ull * 768 * 2);
  u16*     Wsbf    = (u16*)    alloc(256ull * 256 * 2);
  u16*     enc_out = (u16*)    alloc(16ull * 400 * 512 * 2);
  u16*     feat    = (u16*)    alloc(16ull * 400 * 256 * 2);
  float*   hfin    = (float*)  alloc(2 * 16 * 256 * 4);
  float*   cfin    = (float*)  alloc(2 * 16 * 256 * 4);
  float*   h0buf   = (float*)  alloc(16 * 256 * 4);
  float*   c0buf   = (float*)  alloc(16 * 256 * 4);
  float4*  xwd     = (float4*) alloc(50ull * 16 * 256 * 16);
  float*   pg_emb  = (float*)  alloc(800 * 4);
  u32*     hpub    = (u32*)    alloc(8ull * 2048 * 4);
  u32*     flags   = (u32*)    alloc(4 * 32 * 4);
  u32*     dhpub   = (u32*)    alloc(16ull * 256 * 4);   // 16KB h exchange
  u32*     cxch    = (u32*)    alloc(16ull * 512 * 4);   // 32KB ctx exchange
  u32*     dflags  = (u32*)    alloc(16 * 32 * 4);
  u16*     Abf     = (u16*)    alloc(800ull * 768 * 2);
  float*   ltgt_all= (float*)  alloc(800 * 4);
  float*   pg_all  = (float*)  alloc(800 * 4);
  float*   cvl_all = (float*)  alloc(800 * 4);
  float*   sct_all = (float*)  alloc(800 * 4);
  float*   loss_g  = (float*)  alloc(800 * 4);
  float*   valid_g = (float*)  alloc(800 * 4);
  float*   mpart2  = (float*)  alloc(800ull * 125 * 4);
  float*   spart2  = (float*)  alloc(800ull * 125 * 4);
  u16*     vWt     = (u16*)    alloc(32000ull * 768 * 2);

  hipMemsetAsync(flags, 0, 4 * 32 * 4, stream);
  hipMemsetAsync(dflags, 0, 16 * 32 * 4, stream);

  hipLaunchKernelGGL(k_pack_whh2,  dim3(2048),  dim3(256), 0, stream, eWhhF, eWhhB, whhp);
  hipLaunchKernelGGL(k_pack_decwt, dim3(1024),  dim3(256), 0, stream, dWih, dWhh, decwt);
  hipLaunchKernelGGL(k_pack_ws,    dim3(256),   dim3(256), 0, stream, aWs, Wsbf);
  hipLaunchKernelGGL(k_pack_vwt,   dim3(500, 12), dim3(256), 0, stream, vW, vWt);
  hipLaunchKernelGGL(k_enc_pre2,   dim3(800),   dim3(256), 0, stream, src, enc_emb, eWihF, ebF, eWihB, ebB, xw);
  hipLaunchKernelGGL(k_dec_pre,    dim3(800),   dim3(256), 0, stream, dec_in, dec_emb, dWih, db_, pgW, xwd, pg_emb);
  hipLaunchKernelGGL(k_enc_lstm4,  dim3(4),     dim3(512), 0, stream, xw, whhp, enc_out, hfin, cfin, hpub, flags);
  hipLaunchKernelGGL(k_reduce,     dim3(16),    dim3(256), 0, stream, hfin, cfin, rhW, rhb, rcW, rcb, h0buf, c0buf);
  hipLaunchKernelGGL(k_encfeat,    dim3(400),   dim3(256), 0, stream, enc_out, aWh, feat);
  hipLaunchKernelGGL(k_dec_loop4,  dim3(16),    dim3(512), 0, stream,
                     decwt, xwd, h0buf, c0buf, feat, enc_out, src, src_ext, tgt_ext,
                     Wsbf, aWsb, aWc, av, pgW, pg_emb, pgb, pgbias,
                     Abf, pg_all, cvl_all, sct_all, dhpub, cxch, dflags);
  hipLaunchKernelGGL(k_vgemm,  dim3(125, 10), dim3(256), 0, stream, Abf, vWt, vb, tgt_ext, mpart2, spart2, ltgt_all);
  hipLaunchKernelGGL(k_comb2,  dim3(50), dim3(256), 0, stream, mpart2, spart2, ltgt_all,
                     pg_all, cvl_all, sct_all, tgt_ext, lam, loss_g, valid_g);
  hipLaunchKernelGGL(k_final, dim3(1), dim3(256), 0, stream, loss_g, valid_g, (float*)d_out);
}